// Round 11
// baseline (230.553 us; speedup 1.0000x reference)
//
#include <hip/hip_runtime.h>
#include <hip/hip_bf16.h>
#include <math.h>

// B=4, N=1024, D=768, H=12, HD=64, M=100, FF=3072
// Attention EXACTLY banded radius 99. Round 11: occupancy fix for GEMMs —
// B operand moved from LDS to register fragments (global->reg, 1 tile ahead,
// parity-unrolled loop, static frag names). LDS 48->32 KB/block => 4-5
// blocks/CU (was 3). A path (gload_lds + swizzle + dbuf) unchanged.

typedef __attribute__((ext_vector_type(8))) short bf16x8;
typedef __attribute__((ext_vector_type(4))) float f32x4;

#define GLDS16(g, l) __builtin_amdgcn_global_load_lds( \
    (const __attribute__((address_space(1))) void*)(g), \
    (__attribute__((address_space(3))) void*)(l), 16, 0, 0)

__device__ __forceinline__ unsigned short f2bu(float x) {
    union { __hip_bfloat16 h; unsigned short u; } c;
    c.h = __float2bfloat16(x);
    return c.u;
}
__device__ __forceinline__ float bu2f(unsigned short u) {
    union { __hip_bfloat16 h; unsigned short u; } c;
    c.u = u;
    return __bfloat162float(c.h);
}

// ---------------- fused fp32 -> bf16 convert of all 5 tensors ----------------
__global__ void __launch_bounds__(256)
convert_all_kernel(const float* __restrict__ s0, const float* __restrict__ s1,
                   const float* __restrict__ s2, const float* __restrict__ s3,
                   const float* __restrict__ s4,
                   unsigned short* __restrict__ d0, unsigned short* __restrict__ d1,
                   unsigned short* __restrict__ d2, unsigned short* __restrict__ d3,
                   unsigned short* __restrict__ d4)
{
    const int idx = blockIdx.x * 256 + threadIdx.x;
    const float* s; unsigned short* d; int off;
    if (idx < 786432)       { s = s0; d = d0; off = idx; }
    else if (idx < 1228800) { s = s1; d = d1; off = idx - 786432; }
    else if (idx < 1376256) { s = s2; d = d2; off = idx - 1228800; }
    else if (idx < 1966080) { s = s3; d = d3; off = idx - 1376256; }
    else if (idx < 2555904) { s = s4; d = d4; off = idx - 1966080; }
    else return;
    const float4 v = ((const float4*)s)[off];
    ushort4 o;
    o.x = f2bu(v.x); o.y = f2bu(v.y); o.z = f2bu(v.z); o.w = f2bu(v.w);
    ((ushort4*)d)[off] = o;
}

// emb (H,199,HD,1) fp32 -> embpad (H,256,HD) bf16, rows r>=199 zeroed
__global__ void __launch_bounds__(256)
embpad_kernel(const float* __restrict__ rel, unsigned short* __restrict__ embpad)
{
    const int idx = blockIdx.x * 256 + threadIdx.x;
    if (idx >= 12 * 256 * 64) return;
    const int d = idx & 63;
    const int rp = (idx >> 6) & 255;
    const int h = idx >> 14;
    embpad[idx] = (rp < 199) ? f2bu(rel[((h * 199 + rp) << 6) + d]) : (unsigned short)0;
}

// Swizzle helper: LDS(row, c) holds global chunk c ^ (row&7); read chunk ch of
// row r at LDS chunk ch ^ (r&7). Chunks are 8 shorts = 16 B.
#define SWZ_OFF(ch, row7) ((((ch) ^ (row7)) * 8))

// ---------------- bf16 MFMA GEMM, NT, 128x64 tile ----------------
// A: LDS dbuf (2x16KB, swizzled gload_lds). B: register fragments, direct
// global 16B loads, one K-tile prefetched (parity loop; nt always even).
// MODE 0: +bias, scatter q / k / vT bf16. MODE 2: +bias tanh-GELU -> Cb bf16.
// MODE 3: raw partial -> Cb + blockIdx.z*4096*Ndim elements (bf16).
template<int MODE>
__global__ void __launch_bounds__(256, 4)
gemm64_kernel(const unsigned short* __restrict__ A, const unsigned short* __restrict__ Wt,
              const float* __restrict__ bias, unsigned short* __restrict__ Cb,
              int Ndim, int K, int Ksplit,
              unsigned short* __restrict__ qb, unsigned short* __restrict__ kb,
              unsigned short* __restrict__ vTb)
{
    __shared__ short As[2 * 128 * 64];   // 2 x 16 KB (A only)
    const int tid = threadIdx.x;
    const int l = tid & 63;
    const int w = tid >> 6;
    const int wr = w >> 1, wc = w & 1;

    // XCD-aware swizzle of flattened xy (nxy % 8 == 0 for all our grids)
    int flat = blockIdx.y * gridDim.x + blockIdx.x;
    const int nxy = gridDim.x * gridDim.y;
    flat = (flat & 7) * (nxy >> 3) + (flat >> 3);
    const int bx = flat % gridDim.x;
    const int by = flat / gridDim.x;

    const int row0 = by * 128;
    const int col0 = bx * 64;
    const int koff = blockIdx.z * Ksplit;
    const int nt = Ksplit >> 6;          // 12 / 12 / 6 / 24 — always even

    const int lrow = l >> 3;                      // 0..7
    const int lcol = ((l & 7) ^ lrow) * 8;        // pre-swizzled source chunk
    const int l7 = l & 7;
    const int lm = l & 15, lg4 = l >> 4;

    f32x4 acc[4][2];
#pragma unroll
    for (int m = 0; m < 4; ++m)
#pragma unroll
        for (int n = 0; n < 2; ++n) acc[m][n] = (f32x4){0.f, 0.f, 0.f, 0.f};

    // A-tile staging: 4 global_load_lds per wave
#define STAGEA(buf, t) do {                                                       \
    const int k0 = koff + (t) * 64;                                               \
    _Pragma("unroll")                                                             \
    for (int it = 0; it < 4; ++it) {                                              \
        const int c = w * 4 + it;                                                 \
        GLDS16(A + (size_t)(row0 + c * 8 + lrow) * K + k0 + lcol,                 \
               As + (buf) * 8192 + c * 512);                                      \
    }                                                                             \
} while (0)

    // B fragments: 4 x 16B global loads into a named set (static indexing)
#define LOADB(dst, t) do {                                                        \
    const int k0 = koff + (t) * 64;                                               \
    _Pragma("unroll")                                                             \
    for (int kk = 0; kk < 2; ++kk)                                                \
        _Pragma("unroll")                                                         \
        for (int n = 0; n < 2; ++n)                                               \
            dst[kk][n] = *(const bf16x8*)(Wt +                                    \
                (size_t)(col0 + wc * 32 + n * 16 + lm) * K + k0 + (kk * 4 + lg4) * 8); \
} while (0)

#define COMPUTE(buf, Bf) do {                                                     \
    const short* a_ = As + (buf) * 8192;                                          \
    _Pragma("unroll")                                                             \
    for (int kk = 0; kk < 2; ++kk) {                                              \
        const int ch = kk * 4 + lg4;                                              \
        bf16x8 af[4];                                                             \
        _Pragma("unroll")                                                         \
        for (int m = 0; m < 4; ++m)                                               \
            af[m] = *(const bf16x8*)(a_ + (wr * 64 + m * 16 + lm) * 64 + SWZ_OFF(ch, l7)); \
        _Pragma("unroll")                                                         \
        for (int m = 0; m < 4; ++m)                                               \
            _Pragma("unroll")                                                     \
            for (int n = 0; n < 2; ++n)                                           \
                acc[m][n] = __builtin_amdgcn_mfma_f32_16x16x32_bf16(af[m], Bf[kk][n], acc[m][n], 0, 0, 0); \
    }                                                                             \
} while (0)

    bf16x8 BfA[2][2], BfB[2][2];
    STAGEA(0, 0);
    LOADB(BfA, 0);

    for (int t = 0; t < nt; t += 2) {
        // even sub-iteration: compute tile t from buf0 + BfA
        STAGEA(1, t + 1);                 // t+1 < nt always (nt even)
        LOADB(BfB, t + 1);
        asm volatile("s_waitcnt vmcnt(8)" ::: "memory");   // tile t resident
        __builtin_amdgcn_sched_barrier(0);
        __builtin_amdgcn_s_barrier();
        __builtin_amdgcn_s_setprio(1);
        COMPUTE(0, BfA);
        __builtin_amdgcn_s_setprio(0);
        __builtin_amdgcn_s_barrier();     // buf0 reads done

        // odd sub-iteration: compute tile t+1 from buf1 + BfB
        if (t + 2 < nt) {
            STAGEA(0, t + 2);
            LOADB(BfA, t + 2);
            asm volatile("s_waitcnt vmcnt(8)" ::: "memory");
        } else {
            asm volatile("s_waitcnt vmcnt(0)" ::: "memory");
        }
        __builtin_amdgcn_sched_barrier(0);
        __builtin_amdgcn_s_barrier();
        __builtin_amdgcn_s_setprio(1);
        COMPUTE(1, BfB);
        __builtin_amdgcn_s_setprio(0);
        if (t + 2 < nt) __builtin_amdgcn_s_barrier();  // buf1 reads done
    }
#undef STAGEA
#undef LOADB
#undef COMPUTE

    // Epilogue. D map: col = lane&15, row = (lane>>4)*4 + reg
#pragma unroll
    for (int m = 0; m < 4; ++m) {
#pragma unroll
        for (int n = 0; n < 2; ++n) {
#pragma unroll
            for (int r = 0; r < 4; ++r) {
                const int row = row0 + wr * 64 + m * 16 + (l >> 4) * 4 + r;
                const int col = col0 + wc * 32 + n * 16 + (l & 15);
                if (MODE == 0) {
                    const float v = acc[m][n][r] + bias[col];
                    const int which = col / 768;
                    const int rem = col - which * 768;
                    const int h = rem >> 6, d = rem & 63;
                    const int b = row >> 10, nn = row & 1023;
                    if (which == 0)
                        qb[((size_t)(b * 12 + h) * 1024 + nn) * 64 + d] = f2bu(v);
                    else if (which == 1)
                        kb[((size_t)(b * 12 + h) * 1024 + nn) * 64 + d] = f2bu(v);
                    else
                        vTb[((size_t)(b * 12 + h) * 64 + d) * 1024 + nn] = f2bu(v);
                } else if (MODE == 2) {
                    const float v = acc[m][n][r] + bias[col];
                    const float u = 0.7978845608028654f * (v + 0.044715f * v * v * v);
                    const float th = 1.0f - 2.0f / (__expf(2.0f * u) + 1.0f);
                    Cb[(size_t)row * Ndim + col] = f2bu(0.5f * v * (1.0f + th));
                } else {
                    unsigned short* dst = Cb + (size_t)blockIdx.z * 4096 * Ndim;
                    dst[(size_t)row * Ndim + col] = f2bu(acc[m][n][r]);
                }
            }
        }
    }
}

// ---------------- MFMA banded attention (R9, frozen) ----------------
__global__ void __launch_bounds__(256)
attn_mfma_kernel(const unsigned short* __restrict__ qb, const unsigned short* __restrict__ kb,
                 const unsigned short* __restrict__ vTb, const unsigned short* __restrict__ embpad,
                 unsigned short* __restrict__ ctx)
{
    __shared__ __attribute__((aligned(16))) char lds[58368];
    short* Qps = (short*)(lds);
    short* Qs = (short*)(lds);
    short* Stage = (short*)(lds + 8192);
    unsigned short* Spos = (unsigned short*)(lds + 24576);   // [64][264]
    short* PLall = (short*)(lds);                            // [4][16*320] swizzled
    short* Vt = (short*)(lds + 40960);                       // [64][64]

    const int i0 = blockIdx.x * 64;
    const int h = blockIdx.y, b = blockIdx.z;
    const int tid = threadIdx.x;
    const int l = tid & 63, w = tid >> 6;
    const int lm = l & 15, lg4 = l >> 4;
    const int l7 = l & 7;
    const int lrow = l >> 3;
    const int lcolsw = ((l & 7) ^ lrow) * 8;
    const size_t bh = (size_t)(b * 12 + h);

#pragma unroll
    for (int c = 0; c < 2; ++c) {
        const int row = w * 16 + c * 8 + lrow;
        const int iq = i0 + row;
        const int t2 = iq * 4 + b;
        const int b2 = t2 >> 10, n2 = t2 & 1023;
        const unsigned short* g = qb + ((size_t)(b2 * 12 + h) * 1024 + n2) * 64 + lcolsw;
        GLDS16(g, Qps + (w * 16 + c * 8) * 64);
    }
    __syncthreads();

    bf16x8 afp[2];
#pragma unroll
    for (int kk = 0; kk < 2; ++kk)
        afp[kk] = *(const bf16x8*)(Qps + (w * 16 + lm) * 64 + SWZ_OFF(kk * 4 + lg4, l7));

#pragma unroll
    for (int et = 0; et < 4; ++et) {
        __syncthreads();
#pragma unroll
        for (int c = 0; c < 2; ++c) {
            const int row = w * 16 + c * 8 + lrow;
            const unsigned short* g = embpad + ((size_t)h * 256 + et * 64 + row) * 64 + lcolsw;
            GLDS16(g, Stage + (w * 16 + c * 8) * 64);
        }
        __syncthreads();
        f32x4 cp[4];
#pragma unroll
        for (int sub = 0; sub < 4; ++sub) cp[sub] = (f32x4){0.f, 0.f, 0.f, 0.f};
#pragma unroll
        for (int kk = 0; kk < 2; ++kk)
#pragma unroll
            for (int sub = 0; sub < 4; ++sub) {
                const bf16x8 bv = *(const bf16x8*)(Stage + (sub * 16 + lm) * 64 + SWZ_OFF(kk * 4 + lg4, l7));
                cp[sub] = __builtin_amdgcn_mfma_f32_16x16x32_bf16(afp[kk], bv, cp[sub], 0, 0, 0);
            }
#pragma unroll
        for (int sub = 0; sub < 4; ++sub)
#pragma unroll
            for (int r = 0; r < 4; ++r)
                Spos[(w * 16 + lg4 * 4 + r) * 264 + et * 64 + sub * 16 + lm] = f2bu(cp[sub][r]);
    }

#pragma unroll
    for (int c = 0; c < 2; ++c) {
        const int row = w * 16 + c * 8 + lrow;
        const unsigned short* g = qb + (bh * 1024 + i0 + row) * 64 + lcolsw;
        GLDS16(g, Qs + (w * 16 + c * 8) * 64);
    }

    const int jw0 = (i0 > 128) ? i0 - 128 : 0;
    const int hiex = (i0 + 163 < 1024) ? i0 + 163 : 1024;
    const int nt = (hiex - jw0 + 63) >> 6;

    f32x4 s[5][4];
#pragma unroll
    for (int ct = 0; ct < 5; ++ct)
#pragma unroll
        for (int sub = 0; sub < 4; ++sub) s[ct][sub] = (f32x4){0.f, 0.f, 0.f, 0.f};
    bf16x8 afq[2];

#pragma unroll
    for (int ct = 0; ct < 5; ++ct) {
        __syncthreads();
        if (ct < nt) {
#pragma unroll
            for (int c = 0; c < 2; ++c) {
                const int row = w * 16 + c * 8 + lrow;
                const unsigned short* g = kb + (bh * 1024 + jw0 + ct * 64 + row) * 64 + lcolsw;
                GLDS16(g, Stage + (w * 16 + c * 8) * 64);
            }
        }
        __syncthreads();
        if (ct == 0) {
#pragma unroll
            for (int kk = 0; kk < 2; ++kk)
                afq[kk] = *(const bf16x8*)(Qs + (w * 16 + lm) * 64 + SWZ_OFF(kk * 4 + lg4, l7));
        }
        if (ct < nt) {
#pragma unroll
            for (int kk = 0; kk < 2; ++kk)
#pragma unroll
                for (int sub = 0; sub < 4; ++sub) {
                    const bf16x8 bv = *(const bf16x8*)(Stage + (sub * 16 + lm) * 64 + SWZ_OFF(kk * 4 + lg4, l7));
                    s[ct][sub] = __builtin_amdgcn_mfma_f32_16x16x32_bf16(afq[kk], bv, s[ct][sub], 0, 0, 0);
                }
        }
    }

    const int irel = w * 16 + lg4 * 4;
    float mx[4] = {-1e30f, -1e30f, -1e30f, -1e30f};
#pragma unroll
    for (int ct = 0; ct < 5; ++ct)
#pragma unroll
        for (int sub = 0; sub < 4; ++sub)
#pragma unroll
            for (int r = 0; r < 4; ++r) {
                const int i = i0 + irel + r;
                const int j = jw0 + ct * 64 + sub * 16 + lm;
                const int rr = j - i + 99;
                const int rc = (rr < 0) ? 0 : (rr > 198 ? 198 : rr);
                const float ps = bu2f(Spos[(irel + r) * 264 + rc]);
                const bool ok = (ct < nt) && (rr >= 0) && (rr <= 198);
                const float lg = ok ? (0.125f * s[ct][sub][r] + ps) : -1e30f;
                s[ct][sub][r] = lg;
                mx[r] = fmaxf(mx[r], lg);
            }
#pragma unroll
    for (int m = 1; m < 16; m <<= 1)
#pragma unroll
        for (int r = 0; r < 4; ++r) mx[r] = fmaxf(mx[r], __shfl_xor(mx[r], m, 64));

    float sm[4] = {0.f, 0.f, 0.f, 0.f};
#pragma unroll
    for (int ct = 0; ct < 5; ++ct)
#pragma unroll
        for (int sub = 0; sub < 4; ++sub)
#pragma unroll
            for (int r = 0; r < 4; ++r) {
                const float p = __expf(s[ct][sub][r] - mx[r]);
                s[ct][sub][r] = p;
                sm[r] += p;
            }
#pragma unroll
    for (int m = 1; m < 16; m <<= 1)
#pragma unroll
        for (int r = 0; r < 4; ++r) sm[r] += __shfl_xor(sm[r], m, 64);
    float inv[4];
#pragma unroll
    for (int r = 0; r < 4; ++r) inv[r] = 1.0f / sm[r];

    __syncthreads();

    short* PLw = PLall + w * 5120;
#pragma unroll
    for (int ct = 0; ct < 5; ++ct)
#pragma unroll
        for (int sub = 0; sub < 4; ++sub)
#pragma unroll
            for (int r = 0; r < 4; ++r) {
                const int rowrel = lg4 * 4 + r;
                const int colrel = ct * 64 + sub * 16 + lm;
                int byte = rowrel * 640 + colrel * 2;
                byte ^= ((rowrel & 7) << 4);
                *(short*)((char*)PLw + byte) = (short)f2bu(s[ct][sub][r] * inv[r]);
            }

    f32x4 o[4];
#pragma unroll
    for (int sub = 0; sub < 4; ++sub) o[sub] = (f32x4){0.f, 0.f, 0.f, 0.f};
#pragma unroll
    for (int ct = 0; ct < 5; ++ct) {
        if (ct < nt) {
#pragma unroll
            for (int c = 0; c < 2; ++c) {
                const int dd = w * 16 + c * 8 + lrow;
                const unsigned short* g = vTb + (bh * 64 + dd) * 1024 + jw0 + ct * 64 + lcolsw;
                GLDS16(g, Vt + (w * 16 + c * 8) * 64);
            }
        }
        __syncthreads();
        if (ct < nt) {
#pragma unroll
            for (int kk = 0; kk < 2; ++kk) {
                const int colrel = ct * 64 + kk * 32 + lg4 * 8;
                int byte = lm * 640 + colrel * 2;
                byte ^= ((lm & 7) << 4);
                const bf16x8 ap = *(const bf16x8*)((char*)PLw + byte);
#pragma unroll
                for (int sub = 0; sub < 4; ++sub) {
                    const bf16x8 bv = *(const bf16x8*)(Vt + (sub * 16 + lm) * 64 + SWZ_OFF(kk * 4 + lg4, l7));
                    o[sub] = __builtin_amdgcn_mfma_f32_16x16x32_bf16(ap, bv, o[sub], 0, 0, 0);
                }
            }
        }
        __syncthreads();
    }

#pragma unroll
    for (int sub = 0; sub < 4; ++sub)
#pragma unroll
        for (int r = 0; r < 4; ++r) {
            const int i = i0 + w * 16 + lg4 * 4 + r;
            const int d = sub * 16 + lm;
            ctx[((size_t)b * 1024 + i) * 768 + h * 64 + d] = f2bu(o[sub][r]);
        }
}

// ---------------- fused split-K reduce + bias + residual + LayerNorm ----------------
__global__ void __launch_bounds__(256)
ln_fuse_kernel(const unsigned short* __restrict__ p0, const unsigned short* __restrict__ p1,
               const float* __restrict__ bias,
               const float* __restrict__ residf, const unsigned short* __restrict__ residb,
               const float* __restrict__ g, const float* __restrict__ bta,
               float* __restrict__ outf, unsigned short* __restrict__ outb)
{
    const int row = blockIdx.x;
    const int t = threadIdx.x;
    const size_t base = (size_t)row * 768;
    float v[3];
#pragma unroll
    for (int e = 0; e < 3; ++e) {
        const int idx = t + e * 256;
        const float r = residf ? residf[base + idx] : bu2f(residb[base + idx]);
        v[e] = bu2f(p0[base + idx]) + bu2f(p1[base + idx]) + bias[idx] + r;
    }
    __shared__ float red[4];
    float s = v[0] + v[1] + v[2];
#pragma unroll
    for (int off = 32; off > 0; off >>= 1) s += __shfl_down(s, off);
    if ((t & 63) == 0) red[t >> 6] = s;
    __syncthreads();
    const float mu = (red[0] + red[1] + red[2] + red[3]) * (1.0f / 768.0f);
    __syncthreads();
    const float d0 = v[0] - mu, d1 = v[1] - mu, d2 = v[2] - mu;
    float q = d0 * d0 + d1 * d1 + d2 * d2;
#pragma unroll
    for (int off = 32; off > 0; off >>= 1) q += __shfl_down(q, off);
    if ((t & 63) == 0) red[t >> 6] = q;
    __syncthreads();
    const float var = (red[0] + red[1] + red[2] + red[3]) * (1.0f / 768.0f);
    const float rstd = rsqrtf(var + 1e-5f);
    const float y0 = d0 * rstd * g[t] + bta[t];
    const float y1 = d1 * rstd * g[t + 256] + bta[t + 256];
    const float y2 = d2 * rstd * g[t + 512] + bta[t + 512];
    if (outf) { outf[base + t] = y0; outf[base + t + 256] = y1; outf[base + t + 512] = y2; }
    if (outb) { outb[base + t] = f2bu(y0); outb[base + t + 256] = f2bu(y1); outb[base + t + 512] = f2bu(y2); }
}

extern "C" void kernel_launch(void* const* d_in, const int* in_sizes, int n_in,
                              void* d_out, int out_size, void* d_ws, size_t ws_size,
                              hipStream_t stream)
{
    const float* src    = (const float*)d_in[0];
    const float* qkv_w  = (const float*)d_in[1];
    const float* qkv_b  = (const float*)d_in[2];
    const float* rel    = (const float*)d_in[3];
    const float* proj_w = (const float*)d_in[4];
    const float* proj_b = (const float*)d_in[5];
    const float* ln1_g  = (const float*)d_in[6];
    const float* ln1_b  = (const float*)d_in[7];
    const float* fc1_w  = (const float*)d_in[8];
    const float* fc1_b  = (const float*)d_in[9];
    const float* fc2_w  = (const float*)d_in[10];
    const float* fc2_b  = (const float*)d_in[11];
    const float* ln2_g  = (const float*)d_in[12];
    const float* ln2_b  = (const float*)d_in[13];
    float* out = (float*)d_out;
    char* W = (char*)d_ws;

    // Workspace layout (same as R8-R10, peak 55050240 B = 52.5 MB).
    unsigned short* q_b     = (unsigned short*)(W + 0);
    unsigned short* k_b     = (unsigned short*)(W + 6291456);
    unsigned short* vT_b    = (unsigned short*)(W + 12582912);
    unsigned short* src_b   = (unsigned short*)(W + 18874368);
    unsigned short* ctx_b   = (unsigned short*)(W + 18874368);
    unsigned short* h1_b    = (unsigned short*)(W + 0);
    unsigned short* qkvw_b  = (unsigned short*)(W + 25165824);
    unsigned short* PP      = (unsigned short*)(W + 25165824);  // PP0 | PP1 (2 x 6291456 B)
    unsigned short* FP      = (unsigned short*)(W + 25165824);  // FP0 | FP1 (2 x 6291456 B)
    unsigned short* projw_b = (unsigned short*)(W + 37748736);
    unsigned short* fc1w_b  = (unsigned short*)(W + 38928384);
    unsigned short* fc2w_b  = (unsigned short*)(W + 43646976);
    unsigned short* embp_b  = (unsigned short*)(W + 48365568);
    unsigned short* xbuf_b  = (unsigned short*)(W + 48758784);

    // 0) converts
    convert_all_kernel<<<9984, 256, 0, stream>>>(
        src, qkv_w, proj_w, fc1_w, fc2_w, src_b, qkvw_b, projw_b, fc1w_b, fc2w_b);
    embpad_kernel<<<768, 256, 0, stream>>>(rel, embp_b);

    // 1) QKV: (4096x768)@(2304x768)^T -> scatter q/k/vT
    gemm64_kernel<0><<<dim3(36, 32, 1), 256, 0, stream>>>(
        src_b, qkvw_b, qkv_b, nullptr, 2304, 768, 768, q_b, k_b, vT_b);

    // 2) banded MFMA attention -> ctx bf16
    attn_mfma_kernel<<<dim3(16, 12, 4), 256, 0, stream>>>(q_b, k_b, vT_b, embp_b, ctx_b);

    // 3) proj, split-K x2 -> PP0/PP1 partials (bf16)
    gemm64_kernel<3><<<dim3(12, 32, 2), 256, 0, stream>>>(
        ctx_b, projw_b, nullptr, PP, 768, 768, 384, nullptr, nullptr, nullptr);

    // 4) LN1 = PP0+PP1+proj_b+src -> LN -> xbuf_b
    ln_fuse_kernel<<<4096, 256, 0, stream>>>(
        PP, PP + 4096 * 768, proj_b, src, nullptr, ln1_g, ln1_b, nullptr, xbuf_b);

    // 5) fc1 + bias + GELU -> h1 bf16
    gemm64_kernel<2><<<dim3(48, 32, 1), 256, 0, stream>>>(
        xbuf_b, fc1w_b, fc1_b, h1_b, 3072, 768, 768, nullptr, nullptr, nullptr);

    // 6) fc2, split-K x2 (K=3072 -> 2x1536) -> FP0/FP1
    gemm64_kernel<3><<<dim3(12, 32, 2), 256, 0, stream>>>(
        h1_b, fc2w_b, nullptr, FP, 768, 3072, 1536, nullptr, nullptr, nullptr);

    // 7) LN2 = FP0+FP1+fc2_b+xbuf_b -> LN -> out (f32)
    ln_fuse_kernel<<<4096, 256, 0, stream>>>(
        FP, FP + 4096 * 768, fc2_b, nullptr, xbuf_b, ln2_g, ln2_b, out, nullptr);
}

// Round 12
// 188.870 us; speedup vs baseline: 1.2207x; 1.2207x over previous
//
#include <hip/hip_runtime.h>
#include <hip/hip_bf16.h>
#include <math.h>

// B=4, N=1024, D=768, H=12, HD=64, M=100, FF=3072
// Attention EXACTLY banded radius 99. Round 12: revert R11's B-in-registers
// (L2-latency-bound regression). GEMM = m97-proven shape: 128x128 tile,
// 4 waves of 64x64 (2.0 MFMA/ds_read ratio), SINGLE-buffered 32KB LDS
// (5 blocks/CU vs 3), 2-barrier K-loop, T2 swizzle (R9-proven), split-K.

typedef __attribute__((ext_vector_type(8))) short bf16x8;
typedef __attribute__((ext_vector_type(4))) float f32x4;

#define GLDS16(g, l) __builtin_amdgcn_global_load_lds( \
    (const __attribute__((address_space(1))) void*)(g), \
    (__attribute__((address_space(3))) void*)(l), 16, 0, 0)

__device__ __forceinline__ unsigned short f2bu(float x) {
    union { __hip_bfloat16 h; unsigned short u; } c;
    c.h = __float2bfloat16(x);
    return c.u;
}
__device__ __forceinline__ float bu2f(unsigned short u) {
    union { __hip_bfloat16 h; unsigned short u; } c;
    c.u = u;
    return __bfloat162float(c.h);
}

// ---------------- fused fp32 -> bf16 convert of all 5 tensors ----------------
__global__ void __launch_bounds__(256)
convert_all_kernel(const float* __restrict__ s0, const float* __restrict__ s1,
                   const float* __restrict__ s2, const float* __restrict__ s3,
                   const float* __restrict__ s4,
                   unsigned short* __restrict__ d0, unsigned short* __restrict__ d1,
                   unsigned short* __restrict__ d2, unsigned short* __restrict__ d3,
                   unsigned short* __restrict__ d4)
{
    const int idx = blockIdx.x * 256 + threadIdx.x;
    const float* s; unsigned short* d; int off;
    if (idx < 786432)       { s = s0; d = d0; off = idx; }
    else if (idx < 1228800) { s = s1; d = d1; off = idx - 786432; }
    else if (idx < 1376256) { s = s2; d = d2; off = idx - 1228800; }
    else if (idx < 1966080) { s = s3; d = d3; off = idx - 1376256; }
    else if (idx < 2555904) { s = s4; d = d4; off = idx - 1966080; }
    else return;
    const float4 v = ((const float4*)s)[off];
    ushort4 o;
    o.x = f2bu(v.x); o.y = f2bu(v.y); o.z = f2bu(v.z); o.w = f2bu(v.w);
    ((ushort4*)d)[off] = o;
}

// emb (H,199,HD,1) fp32 -> embpad (H,256,HD) bf16, rows r>=199 zeroed
__global__ void __launch_bounds__(256)
embpad_kernel(const float* __restrict__ rel, unsigned short* __restrict__ embpad)
{
    const int idx = blockIdx.x * 256 + threadIdx.x;
    if (idx >= 12 * 256 * 64) return;
    const int d = idx & 63;
    const int rp = (idx >> 6) & 255;
    const int h = idx >> 14;
    embpad[idx] = (rp < 199) ? f2bu(rel[((h * 199 + rp) << 6) + d]) : (unsigned short)0;
}

// Swizzle helper: LDS(row, c) holds global chunk c ^ (row&7); read chunk ch of
// row r at LDS chunk ch ^ (r&7). Chunks are 8 shorts = 16 B.
#define SWZ_OFF(ch, row7) ((((ch) ^ (row7)) * 8))

// ---------------- bf16 MFMA GEMM, NT, 128x128 tile, single-buffer LDS ----------------
// 256 thr = 4 waves (2x2), wave = 64x64 out = 4x4 frags of 16x16x32.
// MODE 0: +bias, scatter q / k / vT bf16. MODE 2: +bias tanh-GELU -> Cb bf16.
// MODE 3: raw partial -> Cb + blockIdx.z*4096*Ndim elements (bf16).
template<int MODE>
__global__ void __launch_bounds__(256)
gemm128_kernel(const unsigned short* __restrict__ A, const unsigned short* __restrict__ Wt,
               const float* __restrict__ bias, unsigned short* __restrict__ Cb,
               int Ndim, int K, int Ksplit,
               unsigned short* __restrict__ qb, unsigned short* __restrict__ kb,
               unsigned short* __restrict__ vTb)
{
    __shared__ short As[128 * 64];   // 16 KB
    __shared__ short Bs[128 * 64];   // 16 KB
    const int tid = threadIdx.x;
    const int l = tid & 63;
    const int w = tid >> 6;
    const int wr = w >> 1, wc = w & 1;

    // XCD-aware swizzle of flattened xy (nxy % 8 == 0 for all our grids)
    int flat = blockIdx.y * gridDim.x + blockIdx.x;
    const int nxy = gridDim.x * gridDim.y;
    flat = (flat & 7) * (nxy >> 3) + (flat >> 3);
    const int bx = flat % gridDim.x;
    const int by = flat / gridDim.x;

    const int row0 = by * 128;
    const int col0 = bx * 128;
    const int koff = blockIdx.z * Ksplit;
    const int nt = Ksplit >> 6;

    const int lrow = l >> 3;                      // 0..7
    const int lcol = ((l & 7) ^ lrow) * 8;        // pre-swizzled source chunk
    const int l7 = l & 7;
    const int lm = l & 15, lg4 = l >> 4;

    f32x4 acc[4][4];
#pragma unroll
    for (int m = 0; m < 4; ++m)
#pragma unroll
        for (int n = 0; n < 4; ++n) acc[m][n] = (f32x4){0.f, 0.f, 0.f, 0.f};

    for (int t = 0; t < nt; ++t) {
        const int k0 = koff + t * 64;
        __syncthreads();                          // prev compute's LDS reads drained
#pragma unroll
        for (int it = 0; it < 4; ++it) {
            const int c = w * 4 + it;             // 16 chunks of 8 rows each
            GLDS16(A + (size_t)(row0 + c * 8 + lrow) * K + k0 + lcol, As + c * 512);
            GLDS16(Wt + (size_t)(col0 + c * 8 + lrow) * K + k0 + lcol, Bs + c * 512);
        }
        __syncthreads();                          // vmcnt(0) drained -> tile ready
#pragma unroll
        for (int kk = 0; kk < 2; ++kk) {
            const int ch = kk * 4 + lg4;          // logical 16B chunk 0..7
            bf16x8 af[4], bfr[4];
#pragma unroll
            for (int m = 0; m < 4; ++m)
                af[m] = *(const bf16x8*)(As + (wr * 64 + m * 16 + lm) * 64 + SWZ_OFF(ch, l7));
#pragma unroll
            for (int n = 0; n < 4; ++n)
                bfr[n] = *(const bf16x8*)(Bs + (wc * 64 + n * 16 + lm) * 64 + SWZ_OFF(ch, l7));
#pragma unroll
            for (int m = 0; m < 4; ++m)
#pragma unroll
                for (int n = 0; n < 4; ++n)
                    acc[m][n] = __builtin_amdgcn_mfma_f32_16x16x32_bf16(af[m], bfr[n], acc[m][n], 0, 0, 0);
        }
    }

    // Epilogue. D map: col = lane&15, row = (lane>>4)*4 + reg
#pragma unroll
    for (int m = 0; m < 4; ++m) {
#pragma unroll
        for (int n = 0; n < 4; ++n) {
#pragma unroll
            for (int r = 0; r < 4; ++r) {
                const int row = row0 + wr * 64 + m * 16 + lg4 * 4 + r;
                const int col = col0 + wc * 64 + n * 16 + lm;
                if (MODE == 0) {
                    const float v = acc[m][n][r] + bias[col];
                    const int which = col / 768;
                    const int rem = col - which * 768;
                    const int h = rem >> 6, d = rem & 63;
                    const int b = row >> 10, nn = row & 1023;
                    if (which == 0)
                        qb[((size_t)(b * 12 + h) * 1024 + nn) * 64 + d] = f2bu(v);
                    else if (which == 1)
                        kb[((size_t)(b * 12 + h) * 1024 + nn) * 64 + d] = f2bu(v);
                    else
                        vTb[((size_t)(b * 12 + h) * 64 + d) * 1024 + nn] = f2bu(v);
                } else if (MODE == 2) {
                    const float v = acc[m][n][r] + bias[col];
                    const float u = 0.7978845608028654f * (v + 0.044715f * v * v * v);
                    const float th = 1.0f - 2.0f / (__expf(2.0f * u) + 1.0f);
                    Cb[(size_t)row * Ndim + col] = f2bu(0.5f * v * (1.0f + th));
                } else {
                    unsigned short* dst = Cb + (size_t)blockIdx.z * 4096 * Ndim;
                    dst[(size_t)row * Ndim + col] = f2bu(acc[m][n][r]);
                }
            }
        }
    }
}

// ---------------- MFMA banded attention (R9, frozen) ----------------
__global__ void __launch_bounds__(256)
attn_mfma_kernel(const unsigned short* __restrict__ qb, const unsigned short* __restrict__ kb,
                 const unsigned short* __restrict__ vTb, const unsigned short* __restrict__ embpad,
                 unsigned short* __restrict__ ctx)
{
    __shared__ __attribute__((aligned(16))) char lds[58368];
    short* Qps = (short*)(lds);
    short* Qs = (short*)(lds);
    short* Stage = (short*)(lds + 8192);
    unsigned short* Spos = (unsigned short*)(lds + 24576);   // [64][264]
    short* PLall = (short*)(lds);                            // [4][16*320] swizzled
    short* Vt = (short*)(lds + 40960);                       // [64][64]

    const int i0 = blockIdx.x * 64;
    const int h = blockIdx.y, b = blockIdx.z;
    const int tid = threadIdx.x;
    const int l = tid & 63, w = tid >> 6;
    const int lm = l & 15, lg4 = l >> 4;
    const int l7 = l & 7;
    const int lrow = l >> 3;
    const int lcolsw = ((l & 7) ^ lrow) * 8;
    const size_t bh = (size_t)(b * 12 + h);

#pragma unroll
    for (int c = 0; c < 2; ++c) {
        const int row = w * 16 + c * 8 + lrow;
        const int iq = i0 + row;
        const int t2 = iq * 4 + b;
        const int b2 = t2 >> 10, n2 = t2 & 1023;
        const unsigned short* g = qb + ((size_t)(b2 * 12 + h) * 1024 + n2) * 64 + lcolsw;
        GLDS16(g, Qps + (w * 16 + c * 8) * 64);
    }
    __syncthreads();

    bf16x8 afp[2];
#pragma unroll
    for (int kk = 0; kk < 2; ++kk)
        afp[kk] = *(const bf16x8*)(Qps + (w * 16 + lm) * 64 + SWZ_OFF(kk * 4 + lg4, l7));

#pragma unroll
    for (int et = 0; et < 4; ++et) {
        __syncthreads();
#pragma unroll
        for (int c = 0; c < 2; ++c) {
            const int row = w * 16 + c * 8 + lrow;
            const unsigned short* g = embpad + ((size_t)h * 256 + et * 64 + row) * 64 + lcolsw;
            GLDS16(g, Stage + (w * 16 + c * 8) * 64);
        }
        __syncthreads();
        f32x4 cp[4];
#pragma unroll
        for (int sub = 0; sub < 4; ++sub) cp[sub] = (f32x4){0.f, 0.f, 0.f, 0.f};
#pragma unroll
        for (int kk = 0; kk < 2; ++kk)
#pragma unroll
            for (int sub = 0; sub < 4; ++sub) {
                const bf16x8 bv = *(const bf16x8*)(Stage + (sub * 16 + lm) * 64 + SWZ_OFF(kk * 4 + lg4, l7));
                cp[sub] = __builtin_amdgcn_mfma_f32_16x16x32_bf16(afp[kk], bv, cp[sub], 0, 0, 0);
            }
#pragma unroll
        for (int sub = 0; sub < 4; ++sub)
#pragma unroll
            for (int r = 0; r < 4; ++r)
                Spos[(w * 16 + lg4 * 4 + r) * 264 + et * 64 + sub * 16 + lm] = f2bu(cp[sub][r]);
    }

#pragma unroll
    for (int c = 0; c < 2; ++c) {
        const int row = w * 16 + c * 8 + lrow;
        const unsigned short* g = qb + (bh * 1024 + i0 + row) * 64 + lcolsw;
        GLDS16(g, Qs + (w * 16 + c * 8) * 64);
    }

    const int jw0 = (i0 > 128) ? i0 - 128 : 0;
    const int hiex = (i0 + 163 < 1024) ? i0 + 163 : 1024;
    const int nt = (hiex - jw0 + 63) >> 6;

    f32x4 s[5][4];
#pragma unroll
    for (int ct = 0; ct < 5; ++ct)
#pragma unroll
        for (int sub = 0; sub < 4; ++sub) s[ct][sub] = (f32x4){0.f, 0.f, 0.f, 0.f};
    bf16x8 afq[2];

#pragma unroll
    for (int ct = 0; ct < 5; ++ct) {
        __syncthreads();
        if (ct < nt) {
#pragma unroll
            for (int c = 0; c < 2; ++c) {
                const int row = w * 16 + c * 8 + lrow;
                const unsigned short* g = kb + (bh * 1024 + jw0 + ct * 64 + row) * 64 + lcolsw;
                GLDS16(g, Stage + (w * 16 + c * 8) * 64);
            }
        }
        __syncthreads();
        if (ct == 0) {
#pragma unroll
            for (int kk = 0; kk < 2; ++kk)
                afq[kk] = *(const bf16x8*)(Qs + (w * 16 + lm) * 64 + SWZ_OFF(kk * 4 + lg4, l7));
        }
        if (ct < nt) {
#pragma unroll
            for (int kk = 0; kk < 2; ++kk)
#pragma unroll
                for (int sub = 0; sub < 4; ++sub) {
                    const bf16x8 bv = *(const bf16x8*)(Stage + (sub * 16 + lm) * 64 + SWZ_OFF(kk * 4 + lg4, l7));
                    s[ct][sub] = __builtin_amdgcn_mfma_f32_16x16x32_bf16(afq[kk], bv, s[ct][sub], 0, 0, 0);
                }
        }
    }

    const int irel = w * 16 + lg4 * 4;
    float mx[4] = {-1e30f, -1e30f, -1e30f, -1e30f};
#pragma unroll
    for (int ct = 0; ct < 5; ++ct)
#pragma unroll
        for (int sub = 0; sub < 4; ++sub)
#pragma unroll
            for (int r = 0; r < 4; ++r) {
                const int i = i0 + irel + r;
                const int j = jw0 + ct * 64 + sub * 16 + lm;
                const int rr = j - i + 99;
                const int rc = (rr < 0) ? 0 : (rr > 198 ? 198 : rr);
                const float ps = bu2f(Spos[(irel + r) * 264 + rc]);
                const bool ok = (ct < nt) && (rr >= 0) && (rr <= 198);
                const float lg = ok ? (0.125f * s[ct][sub][r] + ps) : -1e30f;
                s[ct][sub][r] = lg;
                mx[r] = fmaxf(mx[r], lg);
            }
#pragma unroll
    for (int m = 1; m < 16; m <<= 1)
#pragma unroll
        for (int r = 0; r < 4; ++r) mx[r] = fmaxf(mx[r], __shfl_xor(mx[r], m, 64));

    float sm[4] = {0.f, 0.f, 0.f, 0.f};
#pragma unroll
    for (int ct = 0; ct < 5; ++ct)
#pragma unroll
        for (int sub = 0; sub < 4; ++sub)
#pragma unroll
            for (int r = 0; r < 4; ++r) {
                const float p = __expf(s[ct][sub][r] - mx[r]);
                s[ct][sub][r] = p;
                sm[r] += p;
            }
#pragma unroll
    for (int m = 1; m < 16; m <<= 1)
#pragma unroll
        for (int r = 0; r < 4; ++r) sm[r] += __shfl_xor(sm[r], m, 64);
    float inv[4];
#pragma unroll
    for (int r = 0; r < 4; ++r) inv[r] = 1.0f / sm[r];

    __syncthreads();

    short* PLw = PLall + w * 5120;
#pragma unroll
    for (int ct = 0; ct < 5; ++ct)
#pragma unroll
        for (int sub = 0; sub < 4; ++sub)
#pragma unroll
            for (int r = 0; r < 4; ++r) {
                const int rowrel = lg4 * 4 + r;
                const int colrel = ct * 64 + sub * 16 + lm;
                int byte = rowrel * 640 + colrel * 2;
                byte ^= ((rowrel & 7) << 4);
                *(short*)((char*)PLw + byte) = (short)f2bu(s[ct][sub][r] * inv[r]);
            }

    f32x4 o[4];
#pragma unroll
    for (int sub = 0; sub < 4; ++sub) o[sub] = (f32x4){0.f, 0.f, 0.f, 0.f};
#pragma unroll
    for (int ct = 0; ct < 5; ++ct) {
        if (ct < nt) {
#pragma unroll
            for (int c = 0; c < 2; ++c) {
                const int dd = w * 16 + c * 8 + lrow;
                const unsigned short* g = vTb + (bh * 64 + dd) * 1024 + jw0 + ct * 64 + lcolsw;
                GLDS16(g, Vt + (w * 16 + c * 8) * 64);
            }
        }
        __syncthreads();
        if (ct < nt) {
#pragma unroll
            for (int kk = 0; kk < 2; ++kk) {
                const int colrel = ct * 64 + kk * 32 + lg4 * 8;
                int byte = lm * 640 + colrel * 2;
                byte ^= ((lm & 7) << 4);
                const bf16x8 ap = *(const bf16x8*)((char*)PLw + byte);
#pragma unroll
                for (int sub = 0; sub < 4; ++sub) {
                    const bf16x8 bv = *(const bf16x8*)(Vt + (sub * 16 + lm) * 64 + SWZ_OFF(kk * 4 + lg4, l7));
                    o[sub] = __builtin_amdgcn_mfma_f32_16x16x32_bf16(ap, bv, o[sub], 0, 0, 0);
                }
            }
        }
        __syncthreads();
    }

#pragma unroll
    for (int sub = 0; sub < 4; ++sub)
#pragma unroll
        for (int r = 0; r < 4; ++r) {
            const int i = i0 + w * 16 + lg4 * 4 + r;
            const int d = sub * 16 + lm;
            ctx[((size_t)b * 1024 + i) * 768 + h * 64 + d] = f2bu(o[sub][r]);
        }
}

// ---------------- fused split-K reduce + bias + residual + LayerNorm ----------------
__global__ void __launch_bounds__(256)
ln_fuse_kernel(const unsigned short* __restrict__ p0, const unsigned short* __restrict__ p1,
               const float* __restrict__ bias,
               const float* __restrict__ residf, const unsigned short* __restrict__ residb,
               const float* __restrict__ g, const float* __restrict__ bta,
               float* __restrict__ outf, unsigned short* __restrict__ outb)
{
    const int row = blockIdx.x;
    const int t = threadIdx.x;
    const size_t base = (size_t)row * 768;
    float v[3];
#pragma unroll
    for (int e = 0; e < 3; ++e) {
        const int idx = t + e * 256;
        const float r = residf ? residf[base + idx] : bu2f(residb[base + idx]);
        v[e] = bu2f(p0[base + idx]) + bu2f(p1[base + idx]) + bias[idx] + r;
    }
    __shared__ float red[4];
    float s = v[0] + v[1] + v[2];
#pragma unroll
    for (int off = 32; off > 0; off >>= 1) s += __shfl_down(s, off);
    if ((t & 63) == 0) red[t >> 6] = s;
    __syncthreads();
    const float mu = (red[0] + red[1] + red[2] + red[3]) * (1.0f / 768.0f);
    __syncthreads();
    const float d0 = v[0] - mu, d1 = v[1] - mu, d2 = v[2] - mu;
    float q = d0 * d0 + d1 * d1 + d2 * d2;
#pragma unroll
    for (int off = 32; off > 0; off >>= 1) q += __shfl_down(q, off);
    if ((t & 63) == 0) red[t >> 6] = q;
    __syncthreads();
    const float var = (red[0] + red[1] + red[2] + red[3]) * (1.0f / 768.0f);
    const float rstd = rsqrtf(var + 1e-5f);
    const float y0 = d0 * rstd * g[t] + bta[t];
    const float y1 = d1 * rstd * g[t + 256] + bta[t + 256];
    const float y2 = d2 * rstd * g[t + 512] + bta[t + 512];
    if (outf) { outf[base + t] = y0; outf[base + t + 256] = y1; outf[base + t + 512] = y2; }
    if (outb) { outb[base + t] = f2bu(y0); outb[base + t + 256] = f2bu(y1); outb[base + t + 512] = f2bu(y2); }
}

extern "C" void kernel_launch(void* const* d_in, const int* in_sizes, int n_in,
                              void* d_out, int out_size, void* d_ws, size_t ws_size,
                              hipStream_t stream)
{
    const float* src    = (const float*)d_in[0];
    const float* qkv_w  = (const float*)d_in[1];
    const float* qkv_b  = (const float*)d_in[2];
    const float* rel    = (const float*)d_in[3];
    const float* proj_w = (const float*)d_in[4];
    const float* proj_b = (const float*)d_in[5];
    const float* ln1_g  = (const float*)d_in[6];
    const float* ln1_b  = (const float*)d_in[7];
    const float* fc1_w  = (const float*)d_in[8];
    const float* fc1_b  = (const float*)d_in[9];
    const float* fc2_w  = (const float*)d_in[10];
    const float* fc2_b  = (const float*)d_in[11];
    const float* ln2_g  = (const float*)d_in[12];
    const float* ln2_b  = (const float*)d_in[13];
    float* out = (float*)d_out;
    char* W = (char*)d_ws;

    // Workspace layout (same as R8-R11, peak 55050240 B = 52.5 MB).
    unsigned short* q_b     = (unsigned short*)(W + 0);
    unsigned short* k_b     = (unsigned short*)(W + 6291456);
    unsigned short* vT_b    = (unsigned short*)(W + 12582912);
    unsigned short* src_b   = (unsigned short*)(W + 18874368);
    unsigned short* ctx_b   = (unsigned short*)(W + 18874368);
    unsigned short* h1_b    = (unsigned short*)(W + 0);
    unsigned short* qkvw_b  = (unsigned short*)(W + 25165824);
    unsigned short* PP      = (unsigned short*)(W + 25165824);  // PP0 | PP1 (2 x 6291456 B)
    unsigned short* FP      = (unsigned short*)(W + 25165824);  // FP0 | FP1 (2 x 6291456 B)
    unsigned short* projw_b = (unsigned short*)(W + 37748736);
    unsigned short* fc1w_b  = (unsigned short*)(W + 38928384);
    unsigned short* fc2w_b  = (unsigned short*)(W + 43646976);
    unsigned short* embp_b  = (unsigned short*)(W + 48365568);
    unsigned short* xbuf_b  = (unsigned short*)(W + 48758784);

    // 0) converts
    convert_all_kernel<<<9984, 256, 0, stream>>>(
        src, qkv_w, proj_w, fc1_w, fc2_w, src_b, qkvw_b, projw_b, fc1w_b, fc2w_b);
    embpad_kernel<<<768, 256, 0, stream>>>(rel, embp_b);

    // 1) QKV: (4096x768)@(2304x768)^T -> scatter q/k/vT
    gemm128_kernel<0><<<dim3(18, 32, 1), 256, 0, stream>>>(
        src_b, qkvw_b, qkv_b, nullptr, 2304, 768, 768, q_b, k_b, vT_b);

    // 2) banded MFMA attention -> ctx bf16
    attn_mfma_kernel<<<dim3(16, 12, 4), 256, 0, stream>>>(q_b, k_b, vT_b, embp_b, ctx_b);

    // 3) proj, split-K x2 -> PP0/PP1 partials (bf16)
    gemm128_kernel<3><<<dim3(6, 32, 2), 256, 0, stream>>>(
        ctx_b, projw_b, nullptr, PP, 768, 768, 384, nullptr, nullptr, nullptr);

    // 4) LN1 = PP0+PP1+proj_b+src -> LN -> xbuf_b
    ln_fuse_kernel<<<4096, 256, 0, stream>>>(
        PP, PP + 4096 * 768, proj_b, src, nullptr, ln1_g, ln1_b, nullptr, xbuf_b);

    // 5) fc1 + bias + GELU -> h1 bf16
    gemm128_kernel<2><<<dim3(24, 32, 1), 256, 0, stream>>>(
        xbuf_b, fc1w_b, fc1_b, h1_b, 3072, 768, 768, nullptr, nullptr, nullptr);

    // 6) fc2, split-K x2 (K=3072 -> 2x1536) -> FP0/FP1
    gemm128_kernel<3><<<dim3(6, 32, 2), 256, 0, stream>>>(
        h1_b, fc2w_b, nullptr, FP, 768, 3072, 1536, nullptr, nullptr, nullptr);

    // 7) LN2 = FP0+FP1+fc2_b+xbuf_b -> LN -> out (f32)
    ln_fuse_kernel<<<4096, 256, 0, stream>>>(
        FP, FP + 4096 * 768, fc2_b, nullptr, xbuf_b, ln2_g, ln2_b, out, nullptr);
}

// Round 13
// 169.081 us; speedup vs baseline: 1.3636x; 1.1170x over previous
//
#include <hip/hip_runtime.h>
#include <hip/hip_bf16.h>
#include <math.h>

// B=4, N=1024, D=768, H=12, HD=64, M=100, FF=3072
// Attention EXACTLY banded radius 99. Round 13: restore R9 (measured best,
// 171us): gemm64 128x64 dbuf LDS, one __syncthreads/K-step, T2 swizzle.
// R10 counted-vmcnt (null), R11 B-in-reg (-35%), R12 128x128 single-buf
// (-10%) all falsified. New: embpad fused into convert_all (one fewer
// dispatch).

typedef __attribute__((ext_vector_type(8))) short bf16x8;
typedef __attribute__((ext_vector_type(4))) float f32x4;

#define GLDS16(g, l) __builtin_amdgcn_global_load_lds( \
    (const __attribute__((address_space(1))) void*)(g), \
    (__attribute__((address_space(3))) void*)(l), 16, 0, 0)

__device__ __forceinline__ unsigned short f2bu(float x) {
    union { __hip_bfloat16 h; unsigned short u; } c;
    c.h = __float2bfloat16(x);
    return c.u;
}
__device__ __forceinline__ float bu2f(unsigned short u) {
    union { __hip_bfloat16 h; unsigned short u; } c;
    c.u = u;
    return __bfloat162float(c.h);
}

// ---------------- fused fp32 -> bf16 convert of all 5 tensors + embpad ----------------
// float4-unit ranges: src [0,786432) | qkv_w [..,1228800) | proj_w [..,1376256)
// | fc1_w [..,1966080) | fc2_w [..,2555904). Then PER-ELEMENT embpad range
// [2555904, 2752512): emb (H,199,HD,1) -> embpad (H,256,HD), rows>=199 zero.
__global__ void __launch_bounds__(256)
convert_all_kernel(const float* __restrict__ s0, const float* __restrict__ s1,
                   const float* __restrict__ s2, const float* __restrict__ s3,
                   const float* __restrict__ s4, const float* __restrict__ rel,
                   unsigned short* __restrict__ d0, unsigned short* __restrict__ d1,
                   unsigned short* __restrict__ d2, unsigned short* __restrict__ d3,
                   unsigned short* __restrict__ d4, unsigned short* __restrict__ embp)
{
    const int idx = blockIdx.x * 256 + threadIdx.x;
    const float* s; unsigned short* d; int off;
    if (idx < 786432)       { s = s0; d = d0; off = idx; }
    else if (idx < 1228800) { s = s1; d = d1; off = idx - 786432; }
    else if (idx < 1376256) { s = s2; d = d2; off = idx - 1228800; }
    else if (idx < 1966080) { s = s3; d = d3; off = idx - 1376256; }
    else if (idx < 2555904) { s = s4; d = d4; off = idx - 1966080; }
    else if (idx < 2752512) {
        const int eidx = idx - 2555904;           // (h*256+rp)*64+d
        const int dd = eidx & 63;
        const int rp = (eidx >> 6) & 255;
        const int h = eidx >> 14;
        embp[eidx] = (rp < 199) ? f2bu(rel[((h * 199 + rp) << 6) + dd]) : (unsigned short)0;
        return;
    } else return;
    const float4 v = ((const float4*)s)[off];
    ushort4 o;
    o.x = f2bu(v.x); o.y = f2bu(v.y); o.z = f2bu(v.z); o.w = f2bu(v.w);
    ((ushort4*)d)[off] = o;
}

// Swizzle helper: LDS(row, c) holds global chunk c ^ (row&7); read chunk ch of
// row r at LDS chunk ch ^ (r&7). Chunks are 8 shorts = 16 B.
#define SWZ_OFF(ch, row7) ((((ch) ^ (row7)) * 8))

// ---------------- bf16 MFMA GEMM, NT, 128x64 tile, dbuf LDS, swizzled (R9) ----------------
// MODE 0: +bias, scatter q (b,h,n,d) / k (b,h,n,d) / vT (b,h,d,n) bf16
// MODE 2: +bias, tanh-GELU -> Cb bf16
// MODE 3: raw partial -> Cb + blockIdx.z*4096*Ndim elements (bf16)
template<int MODE>
__global__ void __launch_bounds__(256)
gemm64_kernel(const unsigned short* __restrict__ A, const unsigned short* __restrict__ Wt,
              const float* __restrict__ bias, unsigned short* __restrict__ Cb,
              int Ndim, int K, int Ksplit,
              unsigned short* __restrict__ qb, unsigned short* __restrict__ kb,
              unsigned short* __restrict__ vTb)
{
    __shared__ short As[2 * 128 * 64];   // 2 x 16 KB
    __shared__ short Bs[2 * 64 * 64];    // 2 x 8 KB
    const int tid = threadIdx.x;
    const int l = tid & 63;
    const int w = tid >> 6;
    const int wr = w >> 1, wc = w & 1;

    // XCD-aware swizzle of flattened xy (nxy % 8 == 0 for all our grids)
    int flat = blockIdx.y * gridDim.x + blockIdx.x;
    const int nxy = gridDim.x * gridDim.y;
    flat = (flat & 7) * (nxy >> 3) + (flat >> 3);
    const int bx = flat % gridDim.x;
    const int by = flat / gridDim.x;

    const int row0 = by * 128;
    const int col0 = bx * 64;
    const int koff = blockIdx.z * Ksplit;
    const int nt = Ksplit >> 6;

    const int lrow = l >> 3;                      // 0..7
    const int lcol = ((l & 7) ^ lrow) * 8;        // pre-swizzled source chunk
    const int l7 = l & 7;

    f32x4 acc[4][2];
#pragma unroll
    for (int m = 0; m < 4; ++m)
#pragma unroll
        for (int n = 0; n < 2; ++n) acc[m][n] = (f32x4){0.f, 0.f, 0.f, 0.f};

    // stage K-tile t into buffer buf (LDS dest linear: lane l -> byte l*16)
#define STAGE(buf, t) do {                                                        \
    const int k0 = koff + (t) * 64;                                               \
    _Pragma("unroll")                                                             \
    for (int it = 0; it < 4; ++it) {                                              \
        const int c = w * 4 + it;                                                 \
        GLDS16(A + (size_t)(row0 + c * 8 + lrow) * K + k0 + lcol,                 \
               As + (buf) * 8192 + c * 512);                                      \
    }                                                                             \
    _Pragma("unroll")                                                             \
    for (int it = 0; it < 2; ++it) {                                              \
        const int c = w * 2 + it;                                                 \
        GLDS16(Wt + (size_t)(col0 + c * 8 + lrow) * K + k0 + lcol,                \
               Bs + (buf) * 4096 + c * 512);                                      \
    }                                                                             \
} while (0)

    STAGE(0, 0);
    __syncthreads();                      // vmcnt(0) drained by compiler

    for (int t = 0; t < nt; ++t) {
        const int buf = t & 1;
        if (t + 1 < nt) STAGE(buf ^ 1, t + 1);   // overlaps with compute below
        const short* a = As + buf * 8192;
        const short* bsp = Bs + buf * 4096;
#pragma unroll
        for (int kk = 0; kk < 2; ++kk) {
            const int ch = kk * 4 + (l >> 4);     // logical 16B chunk 0..7
            bf16x8 af[4], bfr[2];
#pragma unroll
            for (int m = 0; m < 4; ++m)
                af[m] = *(const bf16x8*)(a + (wr * 64 + m * 16 + (l & 15)) * 64 + SWZ_OFF(ch, l7));
#pragma unroll
            for (int n = 0; n < 2; ++n)
                bfr[n] = *(const bf16x8*)(bsp + (wc * 32 + n * 16 + (l & 15)) * 64 + SWZ_OFF(ch, l7));
#pragma unroll
            for (int m = 0; m < 4; ++m)
#pragma unroll
                for (int n = 0; n < 2; ++n)
                    acc[m][n] = __builtin_amdgcn_mfma_f32_16x16x32_bf16(af[m], bfr[n], acc[m][n], 0, 0, 0);
        }
        if (t + 1 < nt) __syncthreads();  // uniform; drains stage + cross-wave reads
    }
#undef STAGE

    // Epilogue. D map: col = lane&15, row = (lane>>4)*4 + reg
#pragma unroll
    for (int m = 0; m < 4; ++m) {
#pragma unroll
        for (int n = 0; n < 2; ++n) {
#pragma unroll
            for (int r = 0; r < 4; ++r) {
                const int row = row0 + wr * 64 + m * 16 + (l >> 4) * 4 + r;
                const int col = col0 + wc * 32 + n * 16 + (l & 15);
                if (MODE == 0) {
                    const float v = acc[m][n][r] + bias[col];
                    const int which = col / 768;
                    const int rem = col - which * 768;
                    const int h = rem >> 6, d = rem & 63;
                    const int b = row >> 10, nn = row & 1023;
                    if (which == 0)
                        qb[((size_t)(b * 12 + h) * 1024 + nn) * 64 + d] = f2bu(v);
                    else if (which == 1)
                        kb[((size_t)(b * 12 + h) * 1024 + nn) * 64 + d] = f2bu(v);
                    else
                        vTb[((size_t)(b * 12 + h) * 64 + d) * 1024 + nn] = f2bu(v);
                } else if (MODE == 2) {
                    const float v = acc[m][n][r] + bias[col];
                    // tanh-GELU (max err ~3e-4 vs exact erf form; bf16-noise)
                    const float u = 0.7978845608028654f * (v + 0.044715f * v * v * v);
                    const float th = 1.0f - 2.0f / (__expf(2.0f * u) + 1.0f);
                    Cb[(size_t)row * Ndim + col] = f2bu(0.5f * v * (1.0f + th));
                } else {
                    unsigned short* dst = Cb + (size_t)blockIdx.z * 4096 * Ndim;
                    dst[(size_t)row * Ndim + col] = f2bu(acc[m][n][r]);
                }
            }
        }
    }
}

// ---------------- MFMA banded attention (R9, frozen) ----------------
__global__ void __launch_bounds__(256)
attn_mfma_kernel(const unsigned short* __restrict__ qb, const unsigned short* __restrict__ kb,
                 const unsigned short* __restrict__ vTb, const unsigned short* __restrict__ embpad,
                 unsigned short* __restrict__ ctx)
{
    __shared__ __attribute__((aligned(16))) char lds[58368];
    short* Qps = (short*)(lds);
    short* Qs = (short*)(lds);
    short* Stage = (short*)(lds + 8192);
    unsigned short* Spos = (unsigned short*)(lds + 24576);   // [64][264]
    short* PLall = (short*)(lds);                            // [4][16*320] swizzled
    short* Vt = (short*)(lds + 40960);                       // [64][64]

    const int i0 = blockIdx.x * 64;
    const int h = blockIdx.y, b = blockIdx.z;
    const int tid = threadIdx.x;
    const int l = tid & 63, w = tid >> 6;
    const int lm = l & 15, lg4 = l >> 4;
    const int l7 = l & 7;
    const int lrow = l >> 3;
    const int lcolsw = ((l & 7) ^ lrow) * 8;
    const size_t bh = (size_t)(b * 12 + h);

#pragma unroll
    for (int c = 0; c < 2; ++c) {
        const int row = w * 16 + c * 8 + lrow;
        const int iq = i0 + row;
        const int t2 = iq * 4 + b;
        const int b2 = t2 >> 10, n2 = t2 & 1023;
        const unsigned short* g = qb + ((size_t)(b2 * 12 + h) * 1024 + n2) * 64 + lcolsw;
        GLDS16(g, Qps + (w * 16 + c * 8) * 64);
    }
    __syncthreads();

    bf16x8 afp[2];
#pragma unroll
    for (int kk = 0; kk < 2; ++kk)
        afp[kk] = *(const bf16x8*)(Qps + (w * 16 + lm) * 64 + SWZ_OFF(kk * 4 + lg4, l7));

#pragma unroll
    for (int et = 0; et < 4; ++et) {
        __syncthreads();
#pragma unroll
        for (int c = 0; c < 2; ++c) {
            const int row = w * 16 + c * 8 + lrow;
            const unsigned short* g = embpad + ((size_t)h * 256 + et * 64 + row) * 64 + lcolsw;
            GLDS16(g, Stage + (w * 16 + c * 8) * 64);
        }
        __syncthreads();
        f32x4 cp[4];
#pragma unroll
        for (int sub = 0; sub < 4; ++sub) cp[sub] = (f32x4){0.f, 0.f, 0.f, 0.f};
#pragma unroll
        for (int kk = 0; kk < 2; ++kk)
#pragma unroll
            for (int sub = 0; sub < 4; ++sub) {
                const bf16x8 bv = *(const bf16x8*)(Stage + (sub * 16 + lm) * 64 + SWZ_OFF(kk * 4 + lg4, l7));
                cp[sub] = __builtin_amdgcn_mfma_f32_16x16x32_bf16(afp[kk], bv, cp[sub], 0, 0, 0);
            }
#pragma unroll
        for (int sub = 0; sub < 4; ++sub)
#pragma unroll
            for (int r = 0; r < 4; ++r)
                Spos[(w * 16 + lg4 * 4 + r) * 264 + et * 64 + sub * 16 + lm] = f2bu(cp[sub][r]);
    }

#pragma unroll
    for (int c = 0; c < 2; ++c) {
        const int row = w * 16 + c * 8 + lrow;
        const unsigned short* g = qb + (bh * 1024 + i0 + row) * 64 + lcolsw;
        GLDS16(g, Qs + (w * 16 + c * 8) * 64);
    }

    const int jw0 = (i0 > 128) ? i0 - 128 : 0;
    const int hiex = (i0 + 163 < 1024) ? i0 + 163 : 1024;
    const int nt = (hiex - jw0 + 63) >> 6;

    f32x4 s[5][4];
#pragma unroll
    for (int ct = 0; ct < 5; ++ct)
#pragma unroll
        for (int sub = 0; sub < 4; ++sub) s[ct][sub] = (f32x4){0.f, 0.f, 0.f, 0.f};
    bf16x8 afq[2];

#pragma unroll
    for (int ct = 0; ct < 5; ++ct) {
        __syncthreads();
        if (ct < nt) {
#pragma unroll
            for (int c = 0; c < 2; ++c) {
                const int row = w * 16 + c * 8 + lrow;
                const unsigned short* g = kb + (bh * 1024 + jw0 + ct * 64 + row) * 64 + lcolsw;
                GLDS16(g, Stage + (w * 16 + c * 8) * 64);
            }
        }
        __syncthreads();
        if (ct == 0) {
#pragma unroll
            for (int kk = 0; kk < 2; ++kk)
                afq[kk] = *(const bf16x8*)(Qs + (w * 16 + lm) * 64 + SWZ_OFF(kk * 4 + lg4, l7));
        }
        if (ct < nt) {
#pragma unroll
            for (int kk = 0; kk < 2; ++kk)
#pragma unroll
                for (int sub = 0; sub < 4; ++sub) {
                    const bf16x8 bv = *(const bf16x8*)(Stage + (sub * 16 + lm) * 64 + SWZ_OFF(kk * 4 + lg4, l7));
                    s[ct][sub] = __builtin_amdgcn_mfma_f32_16x16x32_bf16(afq[kk], bv, s[ct][sub], 0, 0, 0);
                }
        }
    }

    const int irel = w * 16 + lg4 * 4;
    float mx[4] = {-1e30f, -1e30f, -1e30f, -1e30f};
#pragma unroll
    for (int ct = 0; ct < 5; ++ct)
#pragma unroll
        for (int sub = 0; sub < 4; ++sub)
#pragma unroll
            for (int r = 0; r < 4; ++r) {
                const int i = i0 + irel + r;
                const int j = jw0 + ct * 64 + sub * 16 + lm;
                const int rr = j - i + 99;
                const int rc = (rr < 0) ? 0 : (rr > 198 ? 198 : rr);
                const float ps = bu2f(Spos[(irel + r) * 264 + rc]);
                const bool ok = (ct < nt) && (rr >= 0) && (rr <= 198);
                const float lg = ok ? (0.125f * s[ct][sub][r] + ps) : -1e30f;
                s[ct][sub][r] = lg;
                mx[r] = fmaxf(mx[r], lg);
            }
#pragma unroll
    for (int m = 1; m < 16; m <<= 1)
#pragma unroll
        for (int r = 0; r < 4; ++r) mx[r] = fmaxf(mx[r], __shfl_xor(mx[r], m, 64));

    float sm[4] = {0.f, 0.f, 0.f, 0.f};
#pragma unroll
    for (int ct = 0; ct < 5; ++ct)
#pragma unroll
        for (int sub = 0; sub < 4; ++sub)
#pragma unroll
            for (int r = 0; r < 4; ++r) {
                const float p = __expf(s[ct][sub][r] - mx[r]);
                s[ct][sub][r] = p;
                sm[r] += p;
            }
#pragma unroll
    for (int m = 1; m < 16; m <<= 1)
#pragma unroll
        for (int r = 0; r < 4; ++r) sm[r] += __shfl_xor(sm[r], m, 64);
    float inv[4];
#pragma unroll
    for (int r = 0; r < 4; ++r) inv[r] = 1.0f / sm[r];

    __syncthreads();

    short* PLw = PLall + w * 5120;
#pragma unroll
    for (int ct = 0; ct < 5; ++ct)
#pragma unroll
        for (int sub = 0; sub < 4; ++sub)
#pragma unroll
            for (int r = 0; r < 4; ++r) {
                const int rowrel = lg4 * 4 + r;
                const int colrel = ct * 64 + sub * 16 + lm;
                int byte = rowrel * 640 + colrel * 2;
                byte ^= ((rowrel & 7) << 4);
                *(short*)((char*)PLw + byte) = (short)f2bu(s[ct][sub][r] * inv[r]);
            }

    f32x4 o[4];
#pragma unroll
    for (int sub = 0; sub < 4; ++sub) o[sub] = (f32x4){0.f, 0.f, 0.f, 0.f};
#pragma unroll
    for (int ct = 0; ct < 5; ++ct) {
        if (ct < nt) {
#pragma unroll
            for (int c = 0; c < 2; ++c) {
                const int dd = w * 16 + c * 8 + lrow;
                const unsigned short* g = vTb + (bh * 64 + dd) * 1024 + jw0 + ct * 64 + lcolsw;
                GLDS16(g, Vt + (w * 16 + c * 8) * 64);
            }
        }
        __syncthreads();
        if (ct < nt) {
#pragma unroll
            for (int kk = 0; kk < 2; ++kk) {
                const int colrel = ct * 64 + kk * 32 + lg4 * 8;
                int byte = lm * 640 + colrel * 2;
                byte ^= ((lm & 7) << 4);
                const bf16x8 ap = *(const bf16x8*)((char*)PLw + byte);
#pragma unroll
                for (int sub = 0; sub < 4; ++sub) {
                    const bf16x8 bv = *(const bf16x8*)(Vt + (sub * 16 + lm) * 64 + SWZ_OFF(kk * 4 + lg4, l7));
                    o[sub] = __builtin_amdgcn_mfma_f32_16x16x32_bf16(ap, bv, o[sub], 0, 0, 0);
                }
            }
        }
        __syncthreads();
    }

#pragma unroll
    for (int sub = 0; sub < 4; ++sub)
#pragma unroll
        for (int r = 0; r < 4; ++r) {
            const int i = i0 + w * 16 + lg4 * 4 + r;
            const int d = sub * 16 + lm;
            ctx[((size_t)b * 1024 + i) * 768 + h * 64 + d] = f2bu(o[sub][r]);
        }
}

// ---------------- fused split-K reduce + bias + residual + LayerNorm ----------------
__global__ void __launch_bounds__(256)
ln_fuse_kernel(const unsigned short* __restrict__ p0, const unsigned short* __restrict__ p1,
               const float* __restrict__ bias,
               const float* __restrict__ residf, const unsigned short* __restrict__ residb,
               const float* __restrict__ g, const float* __restrict__ bta,
               float* __restrict__ outf, unsigned short* __restrict__ outb)
{
    const int row = blockIdx.x;
    const int t = threadIdx.x;
    const size_t base = (size_t)row * 768;
    float v[3];
#pragma unroll
    for (int e = 0; e < 3; ++e) {
        const int idx = t + e * 256;
        const float r = residf ? residf[base + idx] : bu2f(residb[base + idx]);
        v[e] = bu2f(p0[base + idx]) + bu2f(p1[base + idx]) + bias[idx] + r;
    }
    __shared__ float red[4];
    float s = v[0] + v[1] + v[2];
#pragma unroll
    for (int off = 32; off > 0; off >>= 1) s += __shfl_down(s, off);
    if ((t & 63) == 0) red[t >> 6] = s;
    __syncthreads();
    const float mu = (red[0] + red[1] + red[2] + red[3]) * (1.0f / 768.0f);
    __syncthreads();
    const float d0 = v[0] - mu, d1 = v[1] - mu, d2 = v[2] - mu;
    float q = d0 * d0 + d1 * d1 + d2 * d2;
#pragma unroll
    for (int off = 32; off > 0; off >>= 1) q += __shfl_down(q, off);
    if ((t & 63) == 0) red[t >> 6] = q;
    __syncthreads();
    const float var = (red[0] + red[1] + red[2] + red[3]) * (1.0f / 768.0f);
    const float rstd = rsqrtf(var + 1e-5f);
    const float y0 = d0 * rstd * g[t] + bta[t];
    const float y1 = d1 * rstd * g[t + 256] + bta[t + 256];
    const float y2 = d2 * rstd * g[t + 512] + bta[t + 512];
    if (outf) { outf[base + t] = y0; outf[base + t + 256] = y1; outf[base + t + 512] = y2; }
    if (outb) { outb[base + t] = f2bu(y0); outb[base + t + 256] = f2bu(y1); outb[base + t + 512] = f2bu(y2); }
}

extern "C" void kernel_launch(void* const* d_in, const int* in_sizes, int n_in,
                              void* d_out, int out_size, void* d_ws, size_t ws_size,
                              hipStream_t stream)
{
    const float* src    = (const float*)d_in[0];
    const float* qkv_w  = (const float*)d_in[1];
    const float* qkv_b  = (const float*)d_in[2];
    const float* rel    = (const float*)d_in[3];
    const float* proj_w = (const float*)d_in[4];
    const float* proj_b = (const float*)d_in[5];
    const float* ln1_g  = (const float*)d_in[6];
    const float* ln1_b  = (const float*)d_in[7];
    const float* fc1_w  = (const float*)d_in[8];
    const float* fc1_b  = (const float*)d_in[9];
    const float* fc2_w  = (const float*)d_in[10];
    const float* fc2_b  = (const float*)d_in[11];
    const float* ln2_g  = (const float*)d_in[12];
    const float* ln2_b  = (const float*)d_in[13];
    float* out = (float*)d_out;
    char* W = (char*)d_ws;

    // Workspace layout (same as R8-R12, peak 55050240 B = 52.5 MB).
    unsigned short* q_b     = (unsigned short*)(W + 0);
    unsigned short* k_b     = (unsigned short*)(W + 6291456);
    unsigned short* vT_b    = (unsigned short*)(W + 12582912);
    unsigned short* src_b   = (unsigned short*)(W + 18874368);
    unsigned short* ctx_b   = (unsigned short*)(W + 18874368);
    unsigned short* h1_b    = (unsigned short*)(W + 0);
    unsigned short* qkvw_b  = (unsigned short*)(W + 25165824);
    unsigned short* PP      = (unsigned short*)(W + 25165824);  // PP0 | PP1 (2 x 6291456 B)
    unsigned short* FP      = (unsigned short*)(W + 25165824);  // FP0 | FP1 (2 x 6291456 B)
    unsigned short* projw_b = (unsigned short*)(W + 37748736);
    unsigned short* fc1w_b  = (unsigned short*)(W + 38928384);
    unsigned short* fc2w_b  = (unsigned short*)(W + 43646976);
    unsigned short* embp_b  = (unsigned short*)(W + 48365568);
    unsigned short* xbuf_b  = (unsigned short*)(W + 48758784);

    // 0) converts (src, 4 weights, emb-pad — ONE launch)
    convert_all_kernel<<<10752, 256, 0, stream>>>(
        src, qkv_w, proj_w, fc1_w, fc2_w, rel,
        src_b, qkvw_b, projw_b, fc1w_b, fc2w_b, embp_b);

    // 1) QKV: (4096x768)@(2304x768)^T -> scatter q/k/vT
    gemm64_kernel<0><<<dim3(36, 32, 1), 256, 0, stream>>>(
        src_b, qkvw_b, qkv_b, nullptr, 2304, 768, 768, q_b, k_b, vT_b);

    // 2) banded MFMA attention -> ctx bf16
    attn_mfma_kernel<<<dim3(16, 12, 4), 256, 0, stream>>>(q_b, k_b, vT_b, embp_b, ctx_b);

    // 3) proj, split-K x2 -> PP0/PP1 partials (bf16)
    gemm64_kernel<3><<<dim3(12, 32, 2), 256, 0, stream>>>(
        ctx_b, projw_b, nullptr, PP, 768, 768, 384, nullptr, nullptr, nullptr);

    // 4) LN1 = PP0+PP1+proj_b+src -> LN -> xbuf_b
    ln_fuse_kernel<<<4096, 256, 0, stream>>>(
        PP, PP + 4096 * 768, proj_b, src, nullptr, ln1_g, ln1_b, nullptr, xbuf_b);

    // 5) fc1 + bias + GELU -> h1 bf16
    gemm64_kernel<2><<<dim3(48, 32, 1), 256, 0, stream>>>(
        xbuf_b, fc1w_b, fc1_b, h1_b, 3072, 768, 768, nullptr, nullptr, nullptr);

    // 6) fc2, split-K x2 (K=3072 -> 2x1536) -> FP0/FP1
    gemm64_kernel<3><<<dim3(12, 32, 2), 256, 0, stream>>>(
        h1_b, fc2w_b, nullptr, FP, 768, 3072, 1536, nullptr, nullptr, nullptr);

    // 7) LN2 = FP0+FP1+fc2_b+xbuf_b -> LN -> out (f32)
    ln_fuse_kernel<<<4096, 256, 0, stream>>>(
        FP, FP + 4096 * 768, fc2_b, nullptr, xbuf_b, ln2_g, ln2_b, out, nullptr);
}

// Round 15
// 159.935 us; speedup vs baseline: 1.4415x; 1.0572x over previous
//
#include <hip/hip_runtime.h>
#include <hip/hip_bf16.h>
#include <math.h>

// B=4, N=1024, D=768, H=12, HD=64, M=100, FF=3072
// Attention EXACTLY banded radius 99. Round 14 (resubmit after infra flake):
// single change vs R13 — attn LDS compaction: remove dead 8KB hole
// (Spos 24576->16384), total 58368->50176 B => 3 blocks/CU (was 2),
// grid 768 fits in ONE round.

typedef __attribute__((ext_vector_type(8))) short bf16x8;
typedef __attribute__((ext_vector_type(4))) float f32x4;

#define GLDS16(g, l) __builtin_amdgcn_global_load_lds( \
    (const __attribute__((address_space(1))) void*)(g), \
    (__attribute__((address_space(3))) void*)(l), 16, 0, 0)

__device__ __forceinline__ unsigned short f2bu(float x) {
    union { __hip_bfloat16 h; unsigned short u; } c;
    c.h = __float2bfloat16(x);
    return c.u;
}
__device__ __forceinline__ float bu2f(unsigned short u) {
    union { __hip_bfloat16 h; unsigned short u; } c;
    c.u = u;
    return __bfloat162float(c.h);
}

// ---------------- fused fp32 -> bf16 convert of all 5 tensors + embpad ----------------
__global__ void __launch_bounds__(256)
convert_all_kernel(const float* __restrict__ s0, const float* __restrict__ s1,
                   const float* __restrict__ s2, const float* __restrict__ s3,
                   const float* __restrict__ s4, const float* __restrict__ rel,
                   unsigned short* __restrict__ d0, unsigned short* __restrict__ d1,
                   unsigned short* __restrict__ d2, unsigned short* __restrict__ d3,
                   unsigned short* __restrict__ d4, unsigned short* __restrict__ embp)
{
    const int idx = blockIdx.x * 256 + threadIdx.x;
    const float* s; unsigned short* d; int off;
    if (idx < 786432)       { s = s0; d = d0; off = idx; }
    else if (idx < 1228800) { s = s1; d = d1; off = idx - 786432; }
    else if (idx < 1376256) { s = s2; d = d2; off = idx - 1228800; }
    else if (idx < 1966080) { s = s3; d = d3; off = idx - 1376256; }
    else if (idx < 2555904) { s = s4; d = d4; off = idx - 1966080; }
    else if (idx < 2752512) {
        const int eidx = idx - 2555904;           // (h*256+rp)*64+d
        const int dd = eidx & 63;
        const int rp = (eidx >> 6) & 255;
        const int h = eidx >> 14;
        embp[eidx] = (rp < 199) ? f2bu(rel[((h * 199 + rp) << 6) + dd]) : (unsigned short)0;
        return;
    } else return;
    const float4 v = ((const float4*)s)[off];
    ushort4 o;
    o.x = f2bu(v.x); o.y = f2bu(v.y); o.z = f2bu(v.z); o.w = f2bu(v.w);
    ((ushort4*)d)[off] = o;
}

// Swizzle helper: LDS(row, c) holds global chunk c ^ (row&7); read chunk ch of
// row r at LDS chunk ch ^ (r&7). Chunks are 8 shorts = 16 B.
#define SWZ_OFF(ch, row7) ((((ch) ^ (row7)) * 8))

// ---------------- bf16 MFMA GEMM, NT, 128x64 tile, dbuf LDS, swizzled (R9) ----------------
// MODE 0: +bias, scatter q (b,h,n,d) / k (b,h,n,d) / vT (b,h,d,n) bf16
// MODE 2: +bias, tanh-GELU -> Cb bf16
// MODE 3: raw partial -> Cb + blockIdx.z*4096*Ndim elements (bf16)
template<int MODE>
__global__ void __launch_bounds__(256)
gemm64_kernel(const unsigned short* __restrict__ A, const unsigned short* __restrict__ Wt,
              const float* __restrict__ bias, unsigned short* __restrict__ Cb,
              int Ndim, int K, int Ksplit,
              unsigned short* __restrict__ qb, unsigned short* __restrict__ kb,
              unsigned short* __restrict__ vTb)
{
    __shared__ short As[2 * 128 * 64];   // 2 x 16 KB
    __shared__ short Bs[2 * 64 * 64];    // 2 x 8 KB
    const int tid = threadIdx.x;
    const int l = tid & 63;
    const int w = tid >> 6;
    const int wr = w >> 1, wc = w & 1;

    // XCD-aware swizzle of flattened xy (nxy % 8 == 0 for all our grids)
    int flat = blockIdx.y * gridDim.x + blockIdx.x;
    const int nxy = gridDim.x * gridDim.y;
    flat = (flat & 7) * (nxy >> 3) + (flat >> 3);
    const int bx = flat % gridDim.x;
    const int by = flat / gridDim.x;

    const int row0 = by * 128;
    const int col0 = bx * 64;
    const int koff = blockIdx.z * Ksplit;
    const int nt = Ksplit >> 6;

    const int lrow = l >> 3;                      // 0..7
    const int lcol = ((l & 7) ^ lrow) * 8;        // pre-swizzled source chunk
    const int l7 = l & 7;

    f32x4 acc[4][2];
#pragma unroll
    for (int m = 0; m < 4; ++m)
#pragma unroll
        for (int n = 0; n < 2; ++n) acc[m][n] = (f32x4){0.f, 0.f, 0.f, 0.f};

    // stage K-tile t into buffer buf (LDS dest linear: lane l -> byte l*16)
#define STAGE(buf, t) do {                                                        \
    const int k0 = koff + (t) * 64;                                               \
    _Pragma("unroll")                                                             \
    for (int it = 0; it < 4; ++it) {                                              \
        const int c = w * 4 + it;                                                 \
        GLDS16(A + (size_t)(row0 + c * 8 + lrow) * K + k0 + lcol,                 \
               As + (buf) * 8192 + c * 512);                                      \
    }                                                                             \
    _Pragma("unroll")                                                             \
    for (int it = 0; it < 2; ++it) {                                              \
        const int c = w * 2 + it;                                                 \
        GLDS16(Wt + (size_t)(col0 + c * 8 + lrow) * K + k0 + lcol,                \
               Bs + (buf) * 4096 + c * 512);                                      \
    }                                                                             \
} while (0)

    STAGE(0, 0);
    __syncthreads();                      // vmcnt(0) drained by compiler

    for (int t = 0; t < nt; ++t) {
        const int buf = t & 1;
        if (t + 1 < nt) STAGE(buf ^ 1, t + 1);   // overlaps with compute below
        const short* a = As + buf * 8192;
        const short* bsp = Bs + buf * 4096;
#pragma unroll
        for (int kk = 0; kk < 2; ++kk) {
            const int ch = kk * 4 + (l >> 4);     // logical 16B chunk 0..7
            bf16x8 af[4], bfr[2];
#pragma unroll
            for (int m = 0; m < 4; ++m)
                af[m] = *(const bf16x8*)(a + (wr * 64 + m * 16 + (l & 15)) * 64 + SWZ_OFF(ch, l7));
#pragma unroll
            for (int n = 0; n < 2; ++n)
                bfr[n] = *(const bf16x8*)(bsp + (wc * 32 + n * 16 + (l & 15)) * 64 + SWZ_OFF(ch, l7));
#pragma unroll
            for (int m = 0; m < 4; ++m)
#pragma unroll
                for (int n = 0; n < 2; ++n)
                    acc[m][n] = __builtin_amdgcn_mfma_f32_16x16x32_bf16(af[m], bfr[n], acc[m][n], 0, 0, 0);
        }
        if (t + 1 < nt) __syncthreads();  // uniform; drains stage + cross-wave reads
    }
#undef STAGE

    // Epilogue. D map: col = lane&15, row = (lane>>4)*4 + reg
#pragma unroll
    for (int m = 0; m < 4; ++m) {
#pragma unroll
        for (int n = 0; n < 2; ++n) {
#pragma unroll
            for (int r = 0; r < 4; ++r) {
                const int row = row0 + wr * 64 + m * 16 + (l >> 4) * 4 + r;
                const int col = col0 + wc * 32 + n * 16 + (l & 15);
                if (MODE == 0) {
                    const float v = acc[m][n][r] + bias[col];
                    const int which = col / 768;
                    const int rem = col - which * 768;
                    const int h = rem >> 6, d = rem & 63;
                    const int b = row >> 10, nn = row & 1023;
                    if (which == 0)
                        qb[((size_t)(b * 12 + h) * 1024 + nn) * 64 + d] = f2bu(v);
                    else if (which == 1)
                        kb[((size_t)(b * 12 + h) * 1024 + nn) * 64 + d] = f2bu(v);
                    else
                        vTb[((size_t)(b * 12 + h) * 64 + d) * 1024 + nn] = f2bu(v);
                } else if (MODE == 2) {
                    const float v = acc[m][n][r] + bias[col];
                    // tanh-GELU (max err ~3e-4 vs exact erf form; bf16-noise)
                    const float u = 0.7978845608028654f * (v + 0.044715f * v * v * v);
                    const float th = 1.0f - 2.0f / (__expf(2.0f * u) + 1.0f);
                    Cb[(size_t)row * Ndim + col] = f2bu(0.5f * v * (1.0f + th));
                } else {
                    unsigned short* dst = Cb + (size_t)blockIdx.z * 4096 * Ndim;
                    dst[(size_t)row * Ndim + col] = f2bu(acc[m][n][r]);
                }
            }
        }
    }
}

// ---------------- MFMA banded attention (R9 structure; LDS compacted) ----------------
// LDS plan (50176 B => 3 blocks/CU):
//   ph1: Qps@0 (8K) | Stage@8192 (8K) | Spos@16384 (64*264*2=33792, ends 50176)
//   ph2: Qs@0 (alias) | Stage@8192 | Spos read
//   ph3: PL@0 (4*16*320*2=40960, XOR-swizzled) | Vt@40960 (8K, ends 49152)
//   (PL/Vt overwrite Spos only after the post-softmax barrier = Spos last read)
__global__ void __launch_bounds__(256)
attn_mfma_kernel(const unsigned short* __restrict__ qb, const unsigned short* __restrict__ kb,
                 const unsigned short* __restrict__ vTb, const unsigned short* __restrict__ embpad,
                 unsigned short* __restrict__ ctx)
{
    __shared__ __attribute__((aligned(16))) char lds[50176];
    short* Qps = (short*)(lds);
    short* Qs = (short*)(lds);
    short* Stage = (short*)(lds + 8192);
    unsigned short* Spos = (unsigned short*)(lds + 16384);   // [64][264]
    short* PLall = (short*)(lds);                            // [4][16*320] swizzled
    short* Vt = (short*)(lds + 40960);                       // [64][64]

    const int i0 = blockIdx.x * 64;
    const int h = blockIdx.y, b = blockIdx.z;
    const int tid = threadIdx.x;
    const int l = tid & 63, w = tid >> 6;
    const int lm = l & 15, lg4 = l >> 4;
    const int l7 = l & 7;
    const int lrow = l >> 3;
    const int lcolsw = ((l & 7) ^ lrow) * 8;
    const size_t bh = (size_t)(b * 12 + h);

#pragma unroll
    for (int c = 0; c < 2; ++c) {
        const int row = w * 16 + c * 8 + lrow;
        const int iq = i0 + row;
        const int t2 = iq * 4 + b;
        const int b2 = t2 >> 10, n2 = t2 & 1023;
        const unsigned short* g = qb + ((size_t)(b2 * 12 + h) * 1024 + n2) * 64 + lcolsw;
        GLDS16(g, Qps + (w * 16 + c * 8) * 64);
    }
    __syncthreads();

    bf16x8 afp[2];
#pragma unroll
    for (int kk = 0; kk < 2; ++kk)
        afp[kk] = *(const bf16x8*)(Qps + (w * 16 + lm) * 64 + SWZ_OFF(kk * 4 + lg4, l7));

#pragma unroll
    for (int et = 0; et < 4; ++et) {
        __syncthreads();
#pragma unroll
        for (int c = 0; c < 2; ++c) {
            const int row = w * 16 + c * 8 + lrow;
            const unsigned short* g = embpad + ((size_t)h * 256 + et * 64 + row) * 64 + lcolsw;
            GLDS16(g, Stage + (w * 16 + c * 8) * 64);
        }
        __syncthreads();
        f32x4 cp[4];
#pragma unroll
        for (int sub = 0; sub < 4; ++sub) cp[sub] = (f32x4){0.f, 0.f, 0.f, 0.f};
#pragma unroll
        for (int kk = 0; kk < 2; ++kk)
#pragma unroll
            for (int sub = 0; sub < 4; ++sub) {
                const bf16x8 bv = *(const bf16x8*)(Stage + (sub * 16 + lm) * 64 + SWZ_OFF(kk * 4 + lg4, l7));
                cp[sub] = __builtin_amdgcn_mfma_f32_16x16x32_bf16(afp[kk], bv, cp[sub], 0, 0, 0);
            }
#pragma unroll
        for (int sub = 0; sub < 4; ++sub)
#pragma unroll
            for (int r = 0; r < 4; ++r)
                Spos[(w * 16 + lg4 * 4 + r) * 264 + et * 64 + sub * 16 + lm] = f2bu(cp[sub][r]);
    }

#pragma unroll
    for (int c = 0; c < 2; ++c) {
        const int row = w * 16 + c * 8 + lrow;
        const unsigned short* g = qb + (bh * 1024 + i0 + row) * 64 + lcolsw;
        GLDS16(g, Qs + (w * 16 + c * 8) * 64);
    }

    const int jw0 = (i0 > 128) ? i0 - 128 : 0;
    const int hiex = (i0 + 163 < 1024) ? i0 + 163 : 1024;
    const int nt = (hiex - jw0 + 63) >> 6;

    f32x4 s[5][4];
#pragma unroll
    for (int ct = 0; ct < 5; ++ct)
#pragma unroll
        for (int sub = 0; sub < 4; ++sub) s[ct][sub] = (f32x4){0.f, 0.f, 0.f, 0.f};
    bf16x8 afq[2];

#pragma unroll
    for (int ct = 0; ct < 5; ++ct) {
        __syncthreads();
        if (ct < nt) {
#pragma unroll
            for (int c = 0; c < 2; ++c) {
                const int row = w * 16 + c * 8 + lrow;
                const unsigned short* g = kb + (bh * 1024 + jw0 + ct * 64 + row) * 64 + lcolsw;
                GLDS16(g, Stage + (w * 16 + c * 8) * 64);
            }
        }
        __syncthreads();
        if (ct == 0) {
#pragma unroll
            for (int kk = 0; kk < 2; ++kk)
                afq[kk] = *(const bf16x8*)(Qs + (w * 16 + lm) * 64 + SWZ_OFF(kk * 4 + lg4, l7));
        }
        if (ct < nt) {
#pragma unroll
            for (int kk = 0; kk < 2; ++kk)
#pragma unroll
                for (int sub = 0; sub < 4; ++sub) {
                    const bf16x8 bv = *(const bf16x8*)(Stage + (sub * 16 + lm) * 64 + SWZ_OFF(kk * 4 + lg4, l7));
                    s[ct][sub] = __builtin_amdgcn_mfma_f32_16x16x32_bf16(afq[kk], bv, s[ct][sub], 0, 0, 0);
                }
        }
    }

    const int irel = w * 16 + lg4 * 4;
    float mx[4] = {-1e30f, -1e30f, -1e30f, -1e30f};
#pragma unroll
    for (int ct = 0; ct < 5; ++ct)
#pragma unroll
        for (int sub = 0; sub < 4; ++sub)
#pragma unroll
            for (int r = 0; r < 4; ++r) {
                const int i = i0 + irel + r;
                const int j = jw0 + ct * 64 + sub * 16 + lm;
                const int rr = j - i + 99;
                const int rc = (rr < 0) ? 0 : (rr > 198 ? 198 : rr);
                const float ps = bu2f(Spos[(irel + r) * 264 + rc]);
                const bool ok = (ct < nt) && (rr >= 0) && (rr <= 198);
                const float lg = ok ? (0.125f * s[ct][sub][r] + ps) : -1e30f;
                s[ct][sub][r] = lg;
                mx[r] = fmaxf(mx[r], lg);
            }
#pragma unroll
    for (int m = 1; m < 16; m <<= 1)
#pragma unroll
        for (int r = 0; r < 4; ++r) mx[r] = fmaxf(mx[r], __shfl_xor(mx[r], m, 64));

    float sm[4] = {0.f, 0.f, 0.f, 0.f};
#pragma unroll
    for (int ct = 0; ct < 5; ++ct)
#pragma unroll
        for (int sub = 0; sub < 4; ++sub)
#pragma unroll
            for (int r = 0; r < 4; ++r) {
                const float p = __expf(s[ct][sub][r] - mx[r]);
                s[ct][sub][r] = p;
                sm[r] += p;
            }
#pragma unroll
    for (int m = 1; m < 16; m <<= 1)
#pragma unroll
        for (int r = 0; r < 4; ++r) sm[r] += __shfl_xor(sm[r], m, 64);
    float inv[4];
#pragma unroll
    for (int r = 0; r < 4; ++r) inv[r] = 1.0f / sm[r];

    __syncthreads();   // Spos reads done -> PL / Vt regions reusable

    short* PLw = PLall + w * 5120;
#pragma unroll
    for (int ct = 0; ct < 5; ++ct)
#pragma unroll
        for (int sub = 0; sub < 4; ++sub)
#pragma unroll
            for (int r = 0; r < 4; ++r) {
                const int rowrel = lg4 * 4 + r;
                const int colrel = ct * 64 + sub * 16 + lm;
                int byte = rowrel * 640 + colrel * 2;
                byte ^= ((rowrel & 7) << 4);
                *(short*)((char*)PLw + byte) = (short)f2bu(s[ct][sub][r] * inv[r]);
            }

    f32x4 o[4];
#pragma unroll
    for (int sub = 0; sub < 4; ++sub) o[sub] = (f32x4){0.f, 0.f, 0.f, 0.f};
#pragma unroll
    for (int ct = 0; ct < 5; ++ct) {
        if (ct < nt) {
#pragma unroll
            for (int c = 0; c < 2; ++c) {
                const int dd = w * 16 + c * 8 + lrow;
                const unsigned short* g = vTb + (bh * 64 + dd) * 1024 + jw0 + ct * 64 + lcolsw;
                GLDS16(g, Vt + (w * 16 + c * 8) * 64);
            }
        }
        __syncthreads();
        if (ct < nt) {
#pragma unroll
            for (int kk = 0; kk < 2; ++kk) {
                const int colrel = ct * 64 + kk * 32 + lg4 * 8;
                int byte = lm * 640 + colrel * 2;
                byte ^= ((lm & 7) << 4);
                const bf16x8 ap = *(const bf16x8*)((char*)PLw + byte);
#pragma unroll
                for (int sub = 0; sub < 4; ++sub) {
                    const bf16x8 bv = *(const bf16x8*)(Vt + (sub * 16 + lm) * 64 + SWZ_OFF(kk * 4 + lg4, l7));
                    o[sub] = __builtin_amdgcn_mfma_f32_16x16x32_bf16(ap, bv, o[sub], 0, 0, 0);
                }
            }
        }
        __syncthreads();
    }

#pragma unroll
    for (int sub = 0; sub < 4; ++sub)
#pragma unroll
        for (int r = 0; r < 4; ++r) {
            const int i = i0 + w * 16 + lg4 * 4 + r;
            const int d = sub * 16 + lm;
            ctx[((size_t)b * 1024 + i) * 768 + h * 64 + d] = f2bu(o[sub][r]);
        }
}

// ---------------- fused split-K reduce + bias + residual + LayerNorm ----------------
__global__ void __launch_bounds__(256)
ln_fuse_kernel(const unsigned short* __restrict__ p0, const unsigned short* __restrict__ p1,
               const float* __restrict__ bias,
               const float* __restrict__ residf, const unsigned short* __restrict__ residb,
               const float* __restrict__ g, const float* __restrict__ bta,
               float* __restrict__ outf, unsigned short* __restrict__ outb)
{
    const int row = blockIdx.x;
    const int t = threadIdx.x;
    const size_t base = (size_t)row * 768;
    float v[3];
#pragma unroll
    for (int e = 0; e < 3; ++e) {
        const int idx = t + e * 256;
        const float r = residf ? residf[base + idx] : bu2f(residb[base + idx]);
        v[e] = bu2f(p0[base + idx]) + bu2f(p1[base + idx]) + bias[idx] + r;
    }
    __shared__ float red[4];
    float s = v[0] + v[1] + v[2];
#pragma unroll
    for (int off = 32; off > 0; off >>= 1) s += __shfl_down(s, off);
    if ((t & 63) == 0) red[t >> 6] = s;
    __syncthreads();
    const float mu = (red[0] + red[1] + red[2] + red[3]) * (1.0f / 768.0f);
    __syncthreads();
    const float d0 = v[0] - mu, d1 = v[1] - mu, d2 = v[2] - mu;
    float q = d0 * d0 + d1 * d1 + d2 * d2;
#pragma unroll
    for (int off = 32; off > 0; off >>= 1) q += __shfl_down(q, off);
    if ((t & 63) == 0) red[t >> 6] = q;
    __syncthreads();
    const float var = (red[0] + red[1] + red[2] + red[3]) * (1.0f / 768.0f);
    const float rstd = rsqrtf(var + 1e-5f);
    const float y0 = d0 * rstd * g[t] + bta[t];
    const float y1 = d1 * rstd * g[t + 256] + bta[t + 256];
    const float y2 = d2 * rstd * g[t + 512] + bta[t + 512];
    if (outf) { outf[base + t] = y0; outf[base + t + 256] = y1; outf[base + t + 512] = y2; }
    if (outb) { outb[base + t] = f2bu(y0); outb[base + t + 256] = f2bu(y1); outb[base + t + 512] = f2bu(y2); }
}

extern "C" void kernel_launch(void* const* d_in, const int* in_sizes, int n_in,
                              void* d_out, int out_size, void* d_ws, size_t ws_size,
                              hipStream_t stream)
{
    const float* src    = (const float*)d_in[0];
    const float* qkv_w  = (const float*)d_in[1];
    const float* qkv_b  = (const float*)d_in[2];
    const float* rel    = (const float*)d_in[3];
    const float* proj_w = (const float*)d_in[4];
    const float* proj_b = (const float*)d_in[5];
    const float* ln1_g  = (const float*)d_in[6];
    const float* ln1_b  = (const float*)d_in[7];
    const float* fc1_w  = (const float*)d_in[8];
    const float* fc1_b  = (const float*)d_in[9];
    const float* fc2_w  = (const float*)d_in[10];
    const float* fc2_b  = (const float*)d_in[11];
    const float* ln2_g  = (const float*)d_in[12];
    const float* ln2_b  = (const float*)d_in[13];
    float* out = (float*)d_out;
    char* W = (char*)d_ws;

    // Workspace layout (same as R8-R13, peak 55050240 B = 52.5 MB).
    unsigned short* q_b     = (unsigned short*)(W + 0);
    unsigned short* k_b     = (unsigned short*)(W + 6291456);
    unsigned short* vT_b    = (unsigned short*)(W + 12582912);
    unsigned short* src_b   = (unsigned short*)(W + 18874368);
    unsigned short* ctx_b   = (unsigned short*)(W + 18874368);
    unsigned short* h1_b    = (unsigned short*)(W + 0);
    unsigned short* qkvw_b  = (unsigned short*)(W + 25165824);
    unsigned short* PP      = (unsigned short*)(W + 25165824);  // PP0 | PP1 (2 x 6291456 B)
    unsigned short* FP      = (unsigned short*)(W + 25165824);  // FP0 | FP1 (2 x 6291456 B)
    unsigned short* projw_b = (unsigned short*)(W + 37748736);
    unsigned short* fc1w_b  = (unsigned short*)(W + 38928384);
    unsigned short* fc2w_b  = (unsigned short*)(W + 43646976);
    unsigned short* embp_b  = (unsigned short*)(W + 48365568);
    unsigned short* xbuf_b  = (unsigned short*)(W + 48758784);

    // 0) converts (src, 4 weights, emb-pad — ONE launch)
    convert_all_kernel<<<10752, 256, 0, stream>>>(
        src, qkv_w, proj_w, fc1_w, fc2_w, rel,
        src_b, qkvw_b, projw_b, fc1w_b, fc2w_b, embp_b);

    // 1) QKV: (4096x768)@(2304x768)^T -> scatter q/k/vT
    gemm64_kernel<0><<<dim3(36, 32, 1), 256, 0, stream>>>(
        src_b, qkvw_b, qkv_b, nullptr, 2304, 768, 768, q_b, k_b, vT_b);

    // 2) banded MFMA attention -> ctx bf16
    attn_mfma_kernel<<<dim3(16, 12, 4), 256, 0, stream>>>(q_b, k_b, vT_b, embp_b, ctx_b);

    // 3) proj, split-K x2 -> PP0/PP1 partials (bf16)
    gemm64_kernel<3><<<dim3(12, 32, 2), 256, 0, stream>>>(
        ctx_b, projw_b, nullptr, PP, 768, 768, 384, nullptr, nullptr, nullptr);

    // 4) LN1 = PP0+PP1+proj_b+src -> LN -> xbuf_b
    ln_fuse_kernel<<<4096, 256, 0, stream>>>(
        PP, PP + 4096 * 768, proj_b, src, nullptr, ln1_g, ln1_b, nullptr, xbuf_b);

    // 5) fc1 + bias + GELU -> h1 bf16
    gemm64_kernel<2><<<dim3(48, 32, 1), 256, 0, stream>>>(
        xbuf_b, fc1w_b, fc1_b, h1_b, 3072, 768, 768, nullptr, nullptr, nullptr);

    // 6) fc2, split-K x2 (K=3072 -> 2x1536) -> FP0/FP1
    gemm64_kernel<3><<<dim3(12, 32, 2), 256, 0, stream>>>(
        h1_b, fc2w_b, nullptr, FP, 768, 3072, 1536, nullptr, nullptr, nullptr);

    // 7) LN2 = FP0+FP1+fc2_b+xbuf_b -> LN -> out (f32)
    ln_fuse_kernel<<<4096, 256, 0, stream>>>(
        FP, FP + 4096 * 768, fc2_b, nullptr, xbuf_b, ln2_g, ln2_b, out, nullptr);
}

// Round 17
// 159.725 us; speedup vs baseline: 1.4434x; 1.0013x over previous
//
#include <hip/hip_runtime.h>
#include <hip/hip_bf16.h>
#include <math.h>

// B=4, N=1024, D=768, H=12, HD=64, M=100, FF=3072
// Attention EXACTLY banded radius 99. Round 16 (resubmit after infra flake):
// single change vs R15 — LN1 reads the bf16 src copy (src_b, 6.3MB) instead
// of f32 src (12.6MB). src_b relocated to a persistent slot (old slot was
// aliased by ctx_b after attn). Everything else frozen at R15 (159.9 us).

typedef __attribute__((ext_vector_type(8))) short bf16x8;
typedef __attribute__((ext_vector_type(4))) float f32x4;

#define GLDS16(g, l) __builtin_amdgcn_global_load_lds( \
    (const __attribute__((address_space(1))) void*)(g), \
    (__attribute__((address_space(3))) void*)(l), 16, 0, 0)

__device__ __forceinline__ unsigned short f2bu(float x) {
    union { __hip_bfloat16 h; unsigned short u; } c;
    c.h = __float2bfloat16(x);
    return c.u;
}
__device__ __forceinline__ float bu2f(unsigned short u) {
    union { __hip_bfloat16 h; unsigned short u; } c;
    c.u = u;
    return __bfloat162float(c.h);
}

// ---------------- fused fp32 -> bf16 convert of all 5 tensors + embpad ----------------
__global__ void __launch_bounds__(256)
convert_all_kernel(const float* __restrict__ s0, const float* __restrict__ s1,
                   const float* __restrict__ s2, const float* __restrict__ s3,
                   const float* __restrict__ s4, const float* __restrict__ rel,
                   unsigned short* __restrict__ d0, unsigned short* __restrict__ d1,
                   unsigned short* __restrict__ d2, unsigned short* __restrict__ d3,
                   unsigned short* __restrict__ d4, unsigned short* __restrict__ embp)
{
    const int idx = blockIdx.x * 256 + threadIdx.x;
    const float* s; unsigned short* d; int off;
    if (idx < 786432)       { s = s0; d = d0; off = idx; }
    else if (idx < 1228800) { s = s1; d = d1; off = idx - 786432; }
    else if (idx < 1376256) { s = s2; d = d2; off = idx - 1228800; }
    else if (idx < 1966080) { s = s3; d = d3; off = idx - 1376256; }
    else if (idx < 2555904) { s = s4; d = d4; off = idx - 1966080; }
    else if (idx < 2752512) {
        const int eidx = idx - 2555904;           // (h*256+rp)*64+d
        const int dd = eidx & 63;
        const int rp = (eidx >> 6) & 255;
        const int h = eidx >> 14;
        embp[eidx] = (rp < 199) ? f2bu(rel[((h * 199 + rp) << 6) + dd]) : (unsigned short)0;
        return;
    } else return;
    const float4 v = ((const float4*)s)[off];
    ushort4 o;
    o.x = f2bu(v.x); o.y = f2bu(v.y); o.z = f2bu(v.z); o.w = f2bu(v.w);
    ((ushort4*)d)[off] = o;
}

// Swizzle helper: LDS(row, c) holds global chunk c ^ (row&7); read chunk ch of
// row r at LDS chunk ch ^ (r&7). Chunks are 8 shorts = 16 B.
#define SWZ_OFF(ch, row7) ((((ch) ^ (row7)) * 8))

// ---------------- bf16 MFMA GEMM, NT, 128x64 tile, dbuf LDS, swizzled (R9) ----------------
// MODE 0: +bias, scatter q (b,h,n,d) / k (b,h,n,d) / vT (b,h,d,n) bf16
// MODE 2: +bias, tanh-GELU -> Cb bf16
// MODE 3: raw partial -> Cb + blockIdx.z*4096*Ndim elements (bf16)
template<int MODE>
__global__ void __launch_bounds__(256)
gemm64_kernel(const unsigned short* __restrict__ A, const unsigned short* __restrict__ Wt,
              const float* __restrict__ bias, unsigned short* __restrict__ Cb,
              int Ndim, int K, int Ksplit,
              unsigned short* __restrict__ qb, unsigned short* __restrict__ kb,
              unsigned short* __restrict__ vTb)
{
    __shared__ short As[2 * 128 * 64];   // 2 x 16 KB
    __shared__ short Bs[2 * 64 * 64];    // 2 x 8 KB
    const int tid = threadIdx.x;
    const int l = tid & 63;
    const int w = tid >> 6;
    const int wr = w >> 1, wc = w & 1;

    // XCD-aware swizzle of flattened xy (nxy % 8 == 0 for all our grids)
    int flat = blockIdx.y * gridDim.x + blockIdx.x;
    const int nxy = gridDim.x * gridDim.y;
    flat = (flat & 7) * (nxy >> 3) + (flat >> 3);
    const int bx = flat % gridDim.x;
    const int by = flat / gridDim.x;

    const int row0 = by * 128;
    const int col0 = bx * 64;
    const int koff = blockIdx.z * Ksplit;
    const int nt = Ksplit >> 6;

    const int lrow = l >> 3;                      // 0..7
    const int lcol = ((l & 7) ^ lrow) * 8;        // pre-swizzled source chunk
    const int l7 = l & 7;

    f32x4 acc[4][2];
#pragma unroll
    for (int m = 0; m < 4; ++m)
#pragma unroll
        for (int n = 0; n < 2; ++n) acc[m][n] = (f32x4){0.f, 0.f, 0.f, 0.f};

    // stage K-tile t into buffer buf (LDS dest linear: lane l -> byte l*16)
#define STAGE(buf, t) do {                                                        \
    const int k0 = koff + (t) * 64;                                               \
    _Pragma("unroll")                                                             \
    for (int it = 0; it < 4; ++it) {                                              \
        const int c = w * 4 + it;                                                 \
        GLDS16(A + (size_t)(row0 + c * 8 + lrow) * K + k0 + lcol,                 \
               As + (buf) * 8192 + c * 512);                                      \
    }                                                                             \
    _Pragma("unroll")                                                             \
    for (int it = 0; it < 2; ++it) {                                              \
        const int c = w * 2 + it;                                                 \
        GLDS16(Wt + (size_t)(col0 + c * 8 + lrow) * K + k0 + lcol,                \
               Bs + (buf) * 4096 + c * 512);                                      \
    }                                                                             \
} while (0)

    STAGE(0, 0);
    __syncthreads();                      // vmcnt(0) drained by compiler

    for (int t = 0; t < nt; ++t) {
        const int buf = t & 1;
        if (t + 1 < nt) STAGE(buf ^ 1, t + 1);   // overlaps with compute below
        const short* a = As + buf * 8192;
        const short* bsp = Bs + buf * 4096;
#pragma unroll
        for (int kk = 0; kk < 2; ++kk) {
            const int ch = kk * 4 + (l >> 4);     // logical 16B chunk 0..7
            bf16x8 af[4], bfr[2];
#pragma unroll
            for (int m = 0; m < 4; ++m)
                af[m] = *(const bf16x8*)(a + (wr * 64 + m * 16 + (l & 15)) * 64 + SWZ_OFF(ch, l7));
#pragma unroll
            for (int n = 0; n < 2; ++n)
                bfr[n] = *(const bf16x8*)(bsp + (wc * 32 + n * 16 + (l & 15)) * 64 + SWZ_OFF(ch, l7));
#pragma unroll
            for (int m = 0; m < 4; ++m)
#pragma unroll
                for (int n = 0; n < 2; ++n)
                    acc[m][n] = __builtin_amdgcn_mfma_f32_16x16x32_bf16(af[m], bfr[n], acc[m][n], 0, 0, 0);
        }
        if (t + 1 < nt) __syncthreads();  // uniform; drains stage + cross-wave reads
    }
#undef STAGE

    // Epilogue. D map: col = lane&15, row = (lane>>4)*4 + reg
#pragma unroll
    for (int m = 0; m < 4; ++m) {
#pragma unroll
        for (int n = 0; n < 2; ++n) {
#pragma unroll
            for (int r = 0; r < 4; ++r) {
                const int row = row0 + wr * 64 + m * 16 + (l >> 4) * 4 + r;
                const int col = col0 + wc * 32 + n * 16 + (l & 15);
                if (MODE == 0) {
                    const float v = acc[m][n][r] + bias[col];
                    const int which = col / 768;
                    const int rem = col - which * 768;
                    const int h = rem >> 6, d = rem & 63;
                    const int b = row >> 10, nn = row & 1023;
                    if (which == 0)
                        qb[((size_t)(b * 12 + h) * 1024 + nn) * 64 + d] = f2bu(v);
                    else if (which == 1)
                        kb[((size_t)(b * 12 + h) * 1024 + nn) * 64 + d] = f2bu(v);
                    else
                        vTb[((size_t)(b * 12 + h) * 64 + d) * 1024 + nn] = f2bu(v);
                } else if (MODE == 2) {
                    const float v = acc[m][n][r] + bias[col];
                    // tanh-GELU (max err ~3e-4 vs exact erf form; bf16-noise)
                    const float u = 0.7978845608028654f * (v + 0.044715f * v * v * v);
                    const float th = 1.0f - 2.0f / (__expf(2.0f * u) + 1.0f);
                    Cb[(size_t)row * Ndim + col] = f2bu(0.5f * v * (1.0f + th));
                } else {
                    unsigned short* dst = Cb + (size_t)blockIdx.z * 4096 * Ndim;
                    dst[(size_t)row * Ndim + col] = f2bu(acc[m][n][r]);
                }
            }
        }
    }
}

// ---------------- MFMA banded attention (R15, frozen; 50176 B LDS) ----------------
__global__ void __launch_bounds__(256)
attn_mfma_kernel(const unsigned short* __restrict__ qb, const unsigned short* __restrict__ kb,
                 const unsigned short* __restrict__ vTb, const unsigned short* __restrict__ embpad,
                 unsigned short* __restrict__ ctx)
{
    __shared__ __attribute__((aligned(16))) char lds[50176];
    short* Qps = (short*)(lds);
    short* Qs = (short*)(lds);
    short* Stage = (short*)(lds + 8192);
    unsigned short* Spos = (unsigned short*)(lds + 16384);   // [64][264]
    short* PLall = (short*)(lds);                            // [4][16*320] swizzled
    short* Vt = (short*)(lds + 40960);                       // [64][64]

    const int i0 = blockIdx.x * 64;
    const int h = blockIdx.y, b = blockIdx.z;
    const int tid = threadIdx.x;
    const int l = tid & 63, w = tid >> 6;
    const int lm = l & 15, lg4 = l >> 4;
    const int l7 = l & 7;
    const int lrow = l >> 3;
    const int lcolsw = ((l & 7) ^ lrow) * 8;
    const size_t bh = (size_t)(b * 12 + h);

#pragma unroll
    for (int c = 0; c < 2; ++c) {
        const int row = w * 16 + c * 8 + lrow;
        const int iq = i0 + row;
        const int t2 = iq * 4 + b;
        const int b2 = t2 >> 10, n2 = t2 & 1023;
        const unsigned short* g = qb + ((size_t)(b2 * 12 + h) * 1024 + n2) * 64 + lcolsw;
        GLDS16(g, Qps + (w * 16 + c * 8) * 64);
    }
    __syncthreads();

    bf16x8 afp[2];
#pragma unroll
    for (int kk = 0; kk < 2; ++kk)
        afp[kk] = *(const bf16x8*)(Qps + (w * 16 + lm) * 64 + SWZ_OFF(kk * 4 + lg4, l7));

#pragma unroll
    for (int et = 0; et < 4; ++et) {
        __syncthreads();
#pragma unroll
        for (int c = 0; c < 2; ++c) {
            const int row = w * 16 + c * 8 + lrow;
            const unsigned short* g = embpad + ((size_t)h * 256 + et * 64 + row) * 64 + lcolsw;
            GLDS16(g, Stage + (w * 16 + c * 8) * 64);
        }
        __syncthreads();
        f32x4 cp[4];
#pragma unroll
        for (int sub = 0; sub < 4; ++sub) cp[sub] = (f32x4){0.f, 0.f, 0.f, 0.f};
#pragma unroll
        for (int kk = 0; kk < 2; ++kk)
#pragma unroll
            for (int sub = 0; sub < 4; ++sub) {
                const bf16x8 bv = *(const bf16x8*)(Stage + (sub * 16 + lm) * 64 + SWZ_OFF(kk * 4 + lg4, l7));
                cp[sub] = __builtin_amdgcn_mfma_f32_16x16x32_bf16(afp[kk], bv, cp[sub], 0, 0, 0);
            }
#pragma unroll
        for (int sub = 0; sub < 4; ++sub)
#pragma unroll
            for (int r = 0; r < 4; ++r)
                Spos[(w * 16 + lg4 * 4 + r) * 264 + et * 64 + sub * 16 + lm] = f2bu(cp[sub][r]);
    }

#pragma unroll
    for (int c = 0; c < 2; ++c) {
        const int row = w * 16 + c * 8 + lrow;
        const unsigned short* g = qb + (bh * 1024 + i0 + row) * 64 + lcolsw;
        GLDS16(g, Qs + (w * 16 + c * 8) * 64);
    }

    const int jw0 = (i0 > 128) ? i0 - 128 : 0;
    const int hiex = (i0 + 163 < 1024) ? i0 + 163 : 1024;
    const int nt = (hiex - jw0 + 63) >> 6;

    f32x4 s[5][4];
#pragma unroll
    for (int ct = 0; ct < 5; ++ct)
#pragma unroll
        for (int sub = 0; sub < 4; ++sub) s[ct][sub] = (f32x4){0.f, 0.f, 0.f, 0.f};
    bf16x8 afq[2];

#pragma unroll
    for (int ct = 0; ct < 5; ++ct) {
        __syncthreads();
        if (ct < nt) {
#pragma unroll
            for (int c = 0; c < 2; ++c) {
                const int row = w * 16 + c * 8 + lrow;
                const unsigned short* g = kb + (bh * 1024 + jw0 + ct * 64 + row) * 64 + lcolsw;
                GLDS16(g, Stage + (w * 16 + c * 8) * 64);
            }
        }
        __syncthreads();
        if (ct == 0) {
#pragma unroll
            for (int kk = 0; kk < 2; ++kk)
                afq[kk] = *(const bf16x8*)(Qs + (w * 16 + lm) * 64 + SWZ_OFF(kk * 4 + lg4, l7));
        }
        if (ct < nt) {
#pragma unroll
            for (int kk = 0; kk < 2; ++kk)
#pragma unroll
                for (int sub = 0; sub < 4; ++sub) {
                    const bf16x8 bv = *(const bf16x8*)(Stage + (sub * 16 + lm) * 64 + SWZ_OFF(kk * 4 + lg4, l7));
                    s[ct][sub] = __builtin_amdgcn_mfma_f32_16x16x32_bf16(afq[kk], bv, s[ct][sub], 0, 0, 0);
                }
        }
    }

    const int irel = w * 16 + lg4 * 4;
    float mx[4] = {-1e30f, -1e30f, -1e30f, -1e30f};
#pragma unroll
    for (int ct = 0; ct < 5; ++ct)
#pragma unroll
        for (int sub = 0; sub < 4; ++sub)
#pragma unroll
            for (int r = 0; r < 4; ++r) {
                const int i = i0 + irel + r;
                const int j = jw0 + ct * 64 + sub * 16 + lm;
                const int rr = j - i + 99;
                const int rc = (rr < 0) ? 0 : (rr > 198 ? 198 : rr);
                const float ps = bu2f(Spos[(irel + r) * 264 + rc]);
                const bool ok = (ct < nt) && (rr >= 0) && (rr <= 198);
                const float lg = ok ? (0.125f * s[ct][sub][r] + ps) : -1e30f;
                s[ct][sub][r] = lg;
                mx[r] = fmaxf(mx[r], lg);
            }
#pragma unroll
    for (int m = 1; m < 16; m <<= 1)
#pragma unroll
        for (int r = 0; r < 4; ++r) mx[r] = fmaxf(mx[r], __shfl_xor(mx[r], m, 64));

    float sm[4] = {0.f, 0.f, 0.f, 0.f};
#pragma unroll
    for (int ct = 0; ct < 5; ++ct)
#pragma unroll
        for (int sub = 0; sub < 4; ++sub)
#pragma unroll
            for (int r = 0; r < 4; ++r) {
                const float p = __expf(s[ct][sub][r] - mx[r]);
                s[ct][sub][r] = p;
                sm[r] += p;
            }
#pragma unroll
    for (int m = 1; m < 16; m <<= 1)
#pragma unroll
        for (int r = 0; r < 4; ++r) sm[r] += __shfl_xor(sm[r], m, 64);
    float inv[4];
#pragma unroll
    for (int r = 0; r < 4; ++r) inv[r] = 1.0f / sm[r];

    __syncthreads();   // Spos reads done -> PL / Vt regions reusable

    short* PLw = PLall + w * 5120;
#pragma unroll
    for (int ct = 0; ct < 5; ++ct)
#pragma unroll
        for (int sub = 0; sub < 4; ++sub)
#pragma unroll
            for (int r = 0; r < 4; ++r) {
                const int rowrel = lg4 * 4 + r;
                const int colrel = ct * 64 + sub * 16 + lm;
                int byte = rowrel * 640 + colrel * 2;
                byte ^= ((rowrel & 7) << 4);
                *(short*)((char*)PLw + byte) = (short)f2bu(s[ct][sub][r] * inv[r]);
            }

    f32x4 o[4];
#pragma unroll
    for (int sub = 0; sub < 4; ++sub) o[sub] = (f32x4){0.f, 0.f, 0.f, 0.f};
#pragma unroll
    for (int ct = 0; ct < 5; ++ct) {
        if (ct < nt) {
#pragma unroll
            for (int c = 0; c < 2; ++c) {
                const int dd = w * 16 + c * 8 + lrow;
                const unsigned short* g = vTb + (bh * 64 + dd) * 1024 + jw0 + ct * 64 + lcolsw;
                GLDS16(g, Vt + (w * 16 + c * 8) * 64);
            }
        }
        __syncthreads();
        if (ct < nt) {
#pragma unroll
            for (int kk = 0; kk < 2; ++kk) {
                const int colrel = ct * 64 + kk * 32 + lg4 * 8;
                int byte = lm * 640 + colrel * 2;
                byte ^= ((lm & 7) << 4);
                const bf16x8 ap = *(const bf16x8*)((char*)PLw + byte);
#pragma unroll
                for (int sub = 0; sub < 4; ++sub) {
                    const bf16x8 bv = *(const bf16x8*)(Vt + (sub * 16 + lm) * 64 + SWZ_OFF(kk * 4 + lg4, l7));
                    o[sub] = __builtin_amdgcn_mfma_f32_16x16x32_bf16(ap, bv, o[sub], 0, 0, 0);
                }
            }
        }
        __syncthreads();
    }

#pragma unroll
    for (int sub = 0; sub < 4; ++sub)
#pragma unroll
        for (int r = 0; r < 4; ++r) {
            const int i = i0 + w * 16 + lg4 * 4 + r;
            const int d = sub * 16 + lm;
            ctx[((size_t)b * 1024 + i) * 768 + h * 64 + d] = f2bu(o[sub][r]);
        }
}

// ---------------- fused split-K reduce + bias + residual + LayerNorm ----------------
__global__ void __launch_bounds__(256)
ln_fuse_kernel(const unsigned short* __restrict__ p0, const unsigned short* __restrict__ p1,
               const float* __restrict__ bias,
               const float* __restrict__ residf, const unsigned short* __restrict__ residb,
               const float* __restrict__ g, const float* __restrict__ bta,
               float* __restrict__ outf, unsigned short* __restrict__ outb)
{
    const int row = blockIdx.x;
    const int t = threadIdx.x;
    const size_t base = (size_t)row * 768;
    float v[3];
#pragma unroll
    for (int e = 0; e < 3; ++e) {
        const int idx = t + e * 256;
        const float r = residf ? residf[base + idx] : bu2f(residb[base + idx]);
        v[e] = bu2f(p0[base + idx]) + bu2f(p1[base + idx]) + bias[idx] + r;
    }
    __shared__ float red[4];
    float s = v[0] + v[1] + v[2];
#pragma unroll
    for (int off = 32; off > 0; off >>= 1) s += __shfl_down(s, off);
    if ((t & 63) == 0) red[t >> 6] = s;
    __syncthreads();
    const float mu = (red[0] + red[1] + red[2] + red[3]) * (1.0f / 768.0f);
    __syncthreads();
    const float d0 = v[0] - mu, d1 = v[1] - mu, d2 = v[2] - mu;
    float q = d0 * d0 + d1 * d1 + d2 * d2;
#pragma unroll
    for (int off = 32; off > 0; off >>= 1) q += __shfl_down(q, off);
    if ((t & 63) == 0) red[t >> 6] = q;
    __syncthreads();
    const float var = (red[0] + red[1] + red[2] + red[3]) * (1.0f / 768.0f);
    const float rstd = rsqrtf(var + 1e-5f);
    const float y0 = d0 * rstd * g[t] + bta[t];
    const float y1 = d1 * rstd * g[t + 256] + bta[t + 256];
    const float y2 = d2 * rstd * g[t + 512] + bta[t + 512];
    if (outf) { outf[base + t] = y0; outf[base + t + 256] = y1; outf[base + t + 512] = y2; }
    if (outb) { outb[base + t] = f2bu(y0); outb[base + t + 256] = f2bu(y1); outb[base + t + 512] = f2bu(y2); }
}

extern "C" void kernel_launch(void* const* d_in, const int* in_sizes, int n_in,
                              void* d_out, int out_size, void* d_ws, size_t ws_size,
                              hipStream_t stream)
{
    const float* src    = (const float*)d_in[0];
    const float* qkv_w  = (const float*)d_in[1];
    const float* qkv_b  = (const float*)d_in[2];
    const float* rel    = (const float*)d_in[3];
    const float* proj_w = (const float*)d_in[4];
    const float* proj_b = (const float*)d_in[5];
    const float* ln1_g  = (const float*)d_in[6];
    const float* ln1_b  = (const float*)d_in[7];
    const float* fc1_w  = (const float*)d_in[8];
    const float* fc1_b  = (const float*)d_in[9];
    const float* fc2_w  = (const float*)d_in[10];
    const float* fc2_b  = (const float*)d_in[11];
    const float* ln2_g  = (const float*)d_in[12];
    const float* ln2_b  = (const float*)d_in[13];
    float* out = (float*)d_out;
    char* W = (char*)d_ws;

    // Workspace layout: R15 base + src_b relocated to a persistent slot
    // [55050240, 61341696). Peak 61341696 B = 58.5 MB (< 60 MB proven R1).
    // ctx_b [18874368,25165824) no longer aliases src_b.
    unsigned short* q_b     = (unsigned short*)(W + 0);
    unsigned short* k_b     = (unsigned short*)(W + 6291456);
    unsigned short* vT_b    = (unsigned short*)(W + 12582912);
    unsigned short* ctx_b   = (unsigned short*)(W + 18874368);
    unsigned short* h1_b    = (unsigned short*)(W + 0);
    unsigned short* qkvw_b  = (unsigned short*)(W + 25165824);
    unsigned short* PP      = (unsigned short*)(W + 25165824);  // PP0 | PP1 (2 x 6291456 B)
    unsigned short* FP      = (unsigned short*)(W + 25165824);  // FP0 | FP1 (2 x 6291456 B)
    unsigned short* projw_b = (unsigned short*)(W + 37748736);
    unsigned short* fc1w_b  = (unsigned short*)(W + 38928384);
    unsigned short* fc2w_b  = (unsigned short*)(W + 43646976);
    unsigned short* embp_b  = (unsigned short*)(W + 48365568);
    unsigned short* xbuf_b  = (unsigned short*)(W + 48758784);
    unsigned short* src_b   = (unsigned short*)(W + 55050240);  // persistent to LN1

    // 0) converts (src, 4 weights, emb-pad — ONE launch)
    convert_all_kernel<<<10752, 256, 0, stream>>>(
        src, qkv_w, proj_w, fc1_w, fc2_w, rel,
        src_b, qkvw_b, projw_b, fc1w_b, fc2w_b, embp_b);

    // 1) QKV: (4096x768)@(2304x768)^T -> scatter q/k/vT
    gemm64_kernel<0><<<dim3(36, 32, 1), 256, 0, stream>>>(
        src_b, qkvw_b, qkv_b, nullptr, 2304, 768, 768, q_b, k_b, vT_b);

    // 2) banded MFMA attention -> ctx bf16
    attn_mfma_kernel<<<dim3(16, 12, 4), 256, 0, stream>>>(q_b, k_b, vT_b, embp_b, ctx_b);

    // 3) proj, split-K x2 -> PP0/PP1 partials (bf16)
    gemm64_kernel<3><<<dim3(12, 32, 2), 256, 0, stream>>>(
        ctx_b, projw_b, nullptr, PP, 768, 768, 384, nullptr, nullptr, nullptr);

    // 4) LN1 = PP0+PP1+proj_b+src(bf16) -> LN -> xbuf_b
    ln_fuse_kernel<<<4096, 256, 0, stream>>>(
        PP, PP + 4096 * 768, proj_b, nullptr, src_b, ln1_g, ln1_b, nullptr, xbuf_b);

    // 5) fc1 + bias + GELU -> h1 bf16
    gemm64_kernel<2><<<dim3(48, 32, 1), 256, 0, stream>>>(
        xbuf_b, fc1w_b, fc1_b, h1_b, 3072, 768, 768, nullptr, nullptr, nullptr);

    // 6) fc2, split-K x2 (K=3072 -> 2x1536) -> FP0/FP1
    gemm64_kernel<3><<<dim3(12, 32, 2), 256, 0, stream>>>(
        h1_b, fc2w_b, nullptr, FP, 768, 3072, 1536, nullptr, nullptr, nullptr);

    // 7) LN2 = FP0+FP1+fc2_b+xbuf_b -> LN -> out (f32)
    ln_fuse_kernel<<<4096, 256, 0, stream>>>(
        FP, FP + 4096 * 768, fc2_b, nullptr, xbuf_b, ln2_g, ln2_b, out, nullptr);
}